// Round 1
// 667.184 us; speedup vs baseline: 1.0125x; 1.0125x over previous
//
#include <hip/hip_runtime.h>
#include <stdint.h>

typedef unsigned short u16;
typedef __bf16 bf16x8 __attribute__((ext_vector_type(8)));
typedef float   f32x4 __attribute__((ext_vector_type(4)));
typedef u16     u16x8 __attribute__((ext_vector_type(8)));
typedef u16     u16x4 __attribute__((ext_vector_type(4)));

__device__ __forceinline__ float bf2f(u16 u) {
    union { uint32_t i; float f; } c; c.i = ((uint32_t)u) << 16; return c.f;
}
__device__ __forceinline__ u16 f2bf(float f) {
    union { float f; uint32_t i; } c; c.f = f;
    uint32_t r = c.i + 0x7FFFu + ((c.i >> 16) & 1u);   // RNE
    return (u16)(r >> 16);
}
__device__ __forceinline__ u16 f2bf_fast(float f) {    // round-half-up (2 ops)
    union { float f; uint32_t i; } c; c.f = f;
    return (u16)((c.i + 0x8000u) >> 16);
}
// packed f32x2 -> bf16x2 (RNE), one VALU op. No builtin on gfx950 (T12 recipe).
__device__ __forceinline__ uint32_t cvt_pk_bf16(float lo, float hi) {
    uint32_t r;
    asm("v_cvt_pk_bf16_f32 %0, %1, %2" : "=v"(r) : "v"(lo), "v"(hi));
    return r;
}
// async global->LDS, 16B per lane. LDS dest must be wave-uniform base + lane*16.
__device__ __forceinline__ void gload_lds16(const u16* g, u16* l) {
    __builtin_amdgcn_global_load_lds(
        (__attribute__((address_space(1))) void*)(g),
        (__attribute__((address_space(3))) void*)(l), 16, 0, 0);
}

// ---------------- fp32 -> bf16 weight conversion: ONE dispatch, 6 segments ----
// blocks [0,1024) wq | [1024,2048) wk | [2048,3072) wv | [3072,4096) wo
// blocks [4096,8192) w1 | [8192,12288) w2
__global__ __launch_bounds__(256) void cvt_all(
    const float* __restrict__ wq, const float* __restrict__ wk,
    const float* __restrict__ wv, const float* __restrict__ wo,
    const float* __restrict__ w1, const float* __restrict__ w2,
    u16* __restrict__ wqb, u16* __restrict__ wkb, u16* __restrict__ wvb,
    u16* __restrict__ wob, u16* __restrict__ w1b, u16* __restrict__ w2b)
{
    int blk = blockIdx.x;
    const float* src; u16* dst; int off;
    if      (blk < 1024)  { src = wq; dst = wqb; off = blk; }
    else if (blk < 2048)  { src = wk; dst = wkb; off = blk - 1024; }
    else if (blk < 3072)  { src = wv; dst = wvb; off = blk - 2048; }
    else if (blk < 4096)  { src = wo; dst = wob; off = blk - 3072; }
    else if (blk < 8192)  { src = w1; dst = w1b; off = blk - 4096; }
    else                  { src = w2; dst = w2b; off = blk - 8192; }
    int i = off * 1024 + threadIdx.x * 4;
    float4 v = *(const float4*)(src + i);
    u16x4 o; o[0] = f2bf(v.x); o[1] = f2bf(v.y); o[2] = f2bf(v.z); o[3] = f2bf(v.w);
    *(u16x4*)(dst + i) = o;
}

// ---------------- LayerNorm: fp32 in -> bf16 out, one wave per row (D=1024) ----
__global__ __launch_bounds__(256) void ln_kernel(
    const float* __restrict__ x, const float* __restrict__ ga,
    const float* __restrict__ be, u16* __restrict__ out)
{
    const int D = 1024;
    int row  = blockIdx.x * 4 + (threadIdx.x >> 6);
    int lane = threadIdx.x & 63;
    const float* xr = x + (size_t)row * D + lane * 16;
    float f[16];
#pragma unroll
    for (int i = 0; i < 4; ++i) *(float4*)&f[i * 4] = *(const float4*)(xr + i * 4);
    float s = 0.f, s2 = 0.f;
#pragma unroll
    for (int i = 0; i < 16; ++i) { s += f[i]; s2 += f[i] * f[i]; }
#pragma unroll
    for (int off = 1; off < 64; off <<= 1) {
        s  += __shfl_xor(s,  off, 64);
        s2 += __shfl_xor(s2, off, 64);
    }
    float mean = s * (1.0f / 1024.0f);
    float var  = s2 * (1.0f / 1024.0f) - mean * mean;
    var = var < 0.f ? 0.f : var;
    float inv = 1.0f / sqrtf(var + 1e-6f);
    float g[16], b[16];
#pragma unroll
    for (int i = 0; i < 4; ++i) {
        *(float4*)&g[i * 4] = *(const float4*)(ga + lane * 16 + i * 4);
        *(float4*)&b[i * 4] = *(const float4*)(be + lane * 16 + i * 4);
    }
    u16x8 o0, o1;
#pragma unroll
    for (int i = 0; i < 8; ++i) {
        o0[i] = f2bf(g[i]     * (f[i]     - mean) * inv + b[i]);
        o1[i] = f2bf(g[8 + i] * (f[8 + i] - mean) * inv + b[8 + i]);
    }
    u16* orow = out + (size_t)row * D + lane * 16;
    *(u16x8*)(orow)     = o0;
    *(u16x8*)(orow + 8) = o1;
}

// ------- 128x128-tile MFMA GEMM core, BK=64 (two 32-K stages per barrier) ------
// LDS: As/Bs each 128x64 as two [128][32] planes (proven conflict-free layout,
// lane-contiguous for global_load_lds). 32 KB total -> 4 blocks/CU.
__device__ __forceinline__ void gemm_core(
    const u16* __restrict__ A, const u16* __restrict__ W,
    int K, int ldw, int row_a0, int row_w0,
    u16* As, u16* Bs, f32x4 (&acc)[4][4])
{
    int tid  = threadIdx.x;
    int lane = tid & 63;
    int quad = (lane >> 4), l16 = lane & 15;
    int wave = tid >> 6;
    int wr = wave >> 1, wc = wave & 1;
    int srow = tid >> 2, scol = (tid & 3) * 8;
    const u16* a0p = A + (size_t)(row_a0 + srow) * K + scol;
    const u16* a1p = a0p + (size_t)64 * K;
    const u16* b0p = W + (size_t)(row_w0 + srow) * ldw + scol;
    const u16* b1p = b0p + (size_t)64 * ldw;
    u16* la0 = As + tid * 8;            // plane0 rows [0,64)
    u16* la1 = As + 2048 + tid * 8;     // plane0 rows [64,128)
    u16* la2 = As + 4096 + tid * 8;     // plane1 rows [0,64)
    u16* la3 = As + 6144 + tid * 8;     // plane1 rows [64,128)
    u16* lb0 = Bs + tid * 8;
    u16* lb1 = Bs + 2048 + tid * 8;
    u16* lb2 = Bs + 4096 + tid * 8;
    u16* lb3 = Bs + 6144 + tid * 8;

    for (int k0 = 0; k0 < K; k0 += 64) {
        __syncthreads();                       // prev iter's frag reads drained
        gload_lds16(a0p + k0,      la0);
        gload_lds16(a1p + k0,      la1);
        gload_lds16(a0p + k0 + 32, la2);
        gload_lds16(a1p + k0 + 32, la3);
        gload_lds16(b0p + k0,      lb0);
        gload_lds16(b1p + k0,      lb1);
        gload_lds16(b0p + k0 + 32, lb2);
        gload_lds16(b1p + k0 + 32, lb3);
        __syncthreads();                       // vmcnt(0) + barrier
#pragma unroll
        for (int h = 0; h < 2; ++h) {
            const u16* Ah = As + h * 4096;
            const u16* Bh = Bs + h * 4096;
            bf16x8 af[4], bf[4];
#pragma unroll
            for (int mt = 0; mt < 4; ++mt)
                af[mt] = *(const bf16x8*)(&Ah[(wr * 64 + mt * 16 + l16) * 32 + quad * 8]);
#pragma unroll
            for (int nt = 0; nt < 4; ++nt)
                bf[nt] = *(const bf16x8*)(&Bh[(wc * 64 + nt * 16 + l16) * 32 + quad * 8]);
#pragma unroll
            for (int mt = 0; mt < 4; ++mt)
#pragma unroll
                for (int nt = 0; nt < 4; ++nt)
                    acc[mt][nt] = __builtin_amdgcn_mfma_f32_16x16x32_bf16(
                        af[mt], bf[nt], acc[mt][nt], 0, 0, 0);
        }
    }
}

// Generic epilogue variant: C = f(A@W^T + bias) (+resid), fp32 or bf16 out.
template<bool OUTF32>
__global__ __launch_bounds__(256) void gemm128(
    const u16* __restrict__ A, const u16* __restrict__ W,
    const float* __restrict__ bias, const float* __restrict__ resid,
    void* __restrict__ Cp, int M, int N, int K, int ldw, int do_relu)
{
    __shared__ u16 As[128 * 64];
    __shared__ u16 Bs[128 * 64];
    int tid  = threadIdx.x;
    int lane = tid & 63, wave = tid >> 6;
    int quad = lane >> 4, l16 = lane & 15;
    int wr = wave >> 1, wc = wave & 1;
    const int row_a0 = blockIdx.x * 128, row_w0 = blockIdx.y * 128;
    f32x4 acc[4][4] = {};
    gemm_core(A, W, K, ldw, row_a0, row_w0, As, Bs, acc);
#pragma unroll
    for (int mt = 0; mt < 4; ++mt) {
#pragma unroll
        for (int nt = 0; nt < 4; ++nt) {
#pragma unroll
            for (int r = 0; r < 4; ++r) {
                int grow = row_a0 + wr * 64 + mt * 16 + quad * 4 + r;
                int gcol = row_w0 + wc * 64 + nt * 16 + l16;
                float vv = acc[mt][nt][r];
                if (bias)    vv += bias[gcol];
                if (do_relu) vv = vv > 0.f ? vv : 0.f;
                if (resid)   vv += resid[(size_t)grow * N + gcol];
                if (OUTF32) ((float*)Cp)[(size_t)grow * N + gcol] = vv;
                else        ((u16*)Cp)[(size_t)grow * N + gcol] = f2bf(vv);
            }
        }
    }
}

// QKV-fused variant: W is stacked [3072 x 1024]; segment -> q/k/v output.
__global__ __launch_bounds__(256) void gemm128_qkv(
    const u16* __restrict__ A, const u16* __restrict__ Wqkv,
    u16* __restrict__ qo, u16* __restrict__ ko, u16* __restrict__ vo, int K)
{
    __shared__ u16 As[128 * 64];
    __shared__ u16 Bs[128 * 64];
    int tid  = threadIdx.x;
    int lane = tid & 63, wave = tid >> 6;
    int quad = lane >> 4, l16 = lane & 15;
    int wr = wave >> 1, wc = wave & 1;
    const int row_a0 = blockIdx.x * 128, row_w0 = blockIdx.y * 128;
    f32x4 acc[4][4] = {};
    gemm_core(A, Wqkv, K, K, row_a0, row_w0, As, Bs, acc);
    int seg = row_w0 >> 10;
    u16* dst = (seg == 0) ? qo : (seg == 1) ? ko : vo;
    int col0 = row_w0 & 1023;
#pragma unroll
    for (int mt = 0; mt < 4; ++mt) {
#pragma unroll
        for (int nt = 0; nt < 4; ++nt) {
#pragma unroll
            for (int r = 0; r < 4; ++r) {
                int grow = row_a0 + wr * 64 + mt * 16 + quad * 4 + r;
                int gcol = col0 + wc * 64 + nt * 16 + l16;
                dst[(size_t)grow * 1024 + gcol] = f2bf(acc[mt][nt][r]);
            }
        }
    }
}

// -------- MFMA flash attention v2: 128-q blocks (8 waves, 512 thr) ------------
// Changes vs v1 (theory: VALU 64% busy + 1.9e7 LDS conflict cycles):
//  * 128 q-rows/block: K/V staging + V-transpose-pack VALU halved per unit
//    work; LDS 54KB -> 2 blocks/CU = 16 waves/CU (was 40% occupancy).
//  * K staged with global_load_lds into [64][64] tile whose 16B chunks are
//    XOR-swizzled by (row>>2)&7. The B-frag read pattern krow=4*l16+t reads
//    stride-4 rows (row&7 has only 2 values per quarter-phase -> 8-way
//    conflict, the dominant SQ_LDS_BANK_CONFLICT source). (krow>>2)&7 = l16&7
//    spans all 8 chunk slots per phase -> conflict-free. Swizzle applied on
//    the GLOBAL source address (linear LDS dest, G21 both-sides rule).
//  * P -> LDS via v_cvt_pk_bf16_f32 pairs: 2 VALU replace ~12 per r.
// Score-tile t on lane l16 = physical key 4*l16+t (contiguous-key mask int4
// load + one b64 P write per r, unchanged from v1).
__global__ __launch_bounds__(512, 4) void attn_kernel(
    const u16* __restrict__ Q, const u16* __restrict__ Km, const u16* __restrict__ Vm,
    const int* __restrict__ mask, u16* __restrict__ O)
{
    const int S = 2048, DM = 1024;
    const float C1 = 0.18033688f;      // 0.125 * log2(e)
    const float C0 = -11.541560f;      // -8 * log2(e)
    __shared__ u16 Qs[128][72];  // [q][d]
    __shared__ u16 Ks[64 * 64];  // [key][d], 16B-chunk swizzled (see above)
    __shared__ u16 Vt[64][72];   // [d][key]
    __shared__ u16 Ps[128][72];  // [q][key] wave-private rows

    int qt = blockIdx.x, bh = blockIdx.y;
    int b = bh >> 4, h = bh & 15;
    int tid = threadIdx.x;
    int wave = tid >> 6, lane = tid & 63;
    int quad = lane >> 4, l16 = lane & 15;
    size_t base = (size_t)b * S;
    size_t hoff = (size_t)h * 64;

    {   // stage Q tile [128 q][64 d]
        int r = tid >> 2, c0 = (tid & 3) * 16;
        const u16* src = Q + (base + qt * 128 + r) * DM + hoff + c0;
        *(u16x8*)(&Qs[r][c0])     = *(const u16x8*)(src);
        *(u16x8*)(&Qs[r][c0 + 8]) = *(const u16x8*)(src + 8);
    }
    // K stage: LDS unit u = tid (16B units) holds K row (tid>>3), source
    // 16B-chunk (tid&7) ^ ((tid>>5)&7)  [ = (row>>2)&7 ].
    const u16* ksrc = Km + (base + (tid >> 3)) * DM + hoff
                    + ((tid & 7) ^ ((tid >> 5) & 7)) * 8;
    u16* kdst = Ks + tid * 8;
    // V stage: thread packs d-rows d0..d0+3 at key pair 2*kp (4 rows/thread).
    int kp = tid & 31, d0 = (tid >> 5) * 4;
    const u16* vsrc = Vm + (base + kp * 2) * DM + hoff + d0;
    const int* msrc = mask + b * S + 4 * l16;

    __syncthreads();
    const int q0 = wave * 16;
    bf16x8 qf0 = *(const bf16x8*)(&Qs[q0 + l16][quad * 8]);
    bf16x8 qf1 = *(const bf16x8*)(&Qs[q0 + l16][32 + quad * 8]);
    const int swz = (l16 & 7) * 8;       // (krow>>2)&7 for krow = 4*l16+t
    const int u0  = (quad * 8) ^ swz;    // chunk offset h=0; h=1 is u0^32

    float l_r[4] = {0.f, 0.f, 0.f, 0.f};
    f32x4 o[4] = {};

    for (int it = 0; it < 32; ++it) {
        __syncthreads();                 // prev iter's frag reads drained
        gload_lds16(ksrc, kdst);
        ksrc += 64 * DM;
        {
            u16x4 va = *(const u16x4*)(vsrc);
            u16x4 vb = *(const u16x4*)(vsrc + DM);
            vsrc += 64 * DM;
#pragma unroll
            for (int i = 0; i < 4; ++i) {
                uint32_t w = (uint32_t)va[i] | ((uint32_t)vb[i] << 16);
                *(uint32_t*)(&Vt[d0 + i][kp * 2]) = w;
            }
        }
        __syncthreads();                 // vmcnt(0)+lgkmcnt(0) + barrier
        // QK^T: tile t reads K row 4*l16+t -> score col l16 == key 4*l16+t
        f32x4 sc[4] = {};
#pragma unroll
        for (int t = 0; t < 4; ++t) {
            const u16* krp = Ks + (4 * l16 + t) * 64;
            bf16x8 kf0 = *(const bf16x8*)(krp + u0);
            bf16x8 kf1 = *(const bf16x8*)(krp + (u0 ^ 32));
            sc[t] = __builtin_amdgcn_mfma_f32_16x16x32_bf16(qf0, kf0, sc[t], 0, 0, 0);
            sc[t] = __builtin_amdgcn_mfma_f32_16x16x32_bf16(qf1, kf1, sc[t], 0, 0, 0);
        }
        // one int4 mask load covers this lane's 4 contiguous keys
        int4 mk4 = *(const int4*)(msrc); msrc += 64;
        float c0t[4];
        c0t[0] = (mk4.x == 0) ? -1e38f : C0;
        c0t[1] = (mk4.y == 0) ? -1e38f : C0;
        c0t[2] = (mk4.z == 0) ? -1e38f : C0;
        c0t[3] = (mk4.w == 0) ? -1e38f : C0;
#pragma unroll
        for (int r = 0; r < 4; ++r) {
            float p0 = exp2f(fmaf(sc[0][r], C1, c0t[0]));
            float p1 = exp2f(fmaf(sc[1][r], C1, c0t[1]));
            float p2 = exp2f(fmaf(sc[2][r], C1, c0t[2]));
            float p3 = exp2f(fmaf(sc[3][r], C1, c0t[3]));
            l_r[r] += (p0 + p1) + (p2 + p3);
            int prow = q0 + quad * 4 + r;
            uint2 pw;
            pw.x = cvt_pk_bf16(p0, p1);
            pw.y = cvt_pk_bf16(p2, p3);
            *(uint2*)(&Ps[prow][4 * l16]) = pw;   // contiguous keys 4*l16..+3
        }
        // PV: A = P (wave-private rows, natural key order), B = Vt
        bf16x8 pf0 = *(const bf16x8*)(&Ps[q0 + l16][quad * 8]);
        bf16x8 pf1 = *(const bf16x8*)(&Ps[q0 + l16][32 + quad * 8]);
#pragma unroll
        for (int t = 0; t < 4; ++t) {
            bf16x8 vf0 = *(const bf16x8*)(&Vt[t * 16 + l16][quad * 8]);
            bf16x8 vf1 = *(const bf16x8*)(&Vt[t * 16 + l16][32 + quad * 8]);
            o[t] = __builtin_amdgcn_mfma_f32_16x16x32_bf16(pf0, vf0, o[t], 0, 0, 0);
            o[t] = __builtin_amdgcn_mfma_f32_16x16x32_bf16(pf1, vf1, o[t], 0, 0, 0);
        }
    }
    // one 16-lane reduction per row, then epilogue
#pragma unroll
    for (int r = 0; r < 4; ++r) {
#pragma unroll
        for (int off = 1; off < 16; off <<= 1) l_r[r] += __shfl_xor(l_r[r], off, 16);
        float inv = 1.0f / l_r[r];
        u16* dst = O + (base + qt * 128 + q0 + quad * 4 + r) * DM + hoff + l16;
#pragma unroll
        for (int t = 0; t < 4; ++t) dst[t * 16] = f2bf(o[t][r] * inv);
    }
}

// -------------------------------------------------------------------------------
// Workspace budget: 72 MB (proven). ws[0..6)MB wq|wk|wv stacked; ws[6..8) wo;
// ws[8..24) w1,w2; ws[24..40) xn; ws[40..56) q; ws[40..72) hb.
// d_out doubles as k/v (bf16) then x1 (fp32).
extern "C" void kernel_launch(void* const* d_in, const int* in_sizes, int n_in,
                              void* d_out, int out_size, void* d_ws, size_t ws_size,
                              hipStream_t stream)
{
    (void)in_sizes; (void)n_in; (void)out_size; (void)ws_size;
    const float* x    = (const float*)d_in[0];
    const int*   mask = (const int*)d_in[1];
    const float* wq   = (const float*)d_in[2];
    const float* wk   = (const float*)d_in[3];
    const float* wv   = (const float*)d_in[4];
    const float* wo   = (const float*)d_in[5];
    const float* ln1a = (const float*)d_in[6];
    const float* ln1b = (const float*)d_in[7];
    const float* ln2a = (const float*)d_in[8];
    const float* ln2b = (const float*)d_in[9];
    const float* w1   = (const float*)d_in[10];
    const float* b1   = (const float*)d_in[11];
    const float* w2   = (const float*)d_in[12];
    const float* b2   = (const float*)d_in[13];

    const int M = 8192, D = 1024, F = 4096;
    char* ws = (char*)d_ws;
    u16*  wqkv = (u16*)(ws);                  // stacked 3072x1024
    u16*  wqb = wqkv;
    u16*  wkb = (u16*)(ws + (2u  << 20));
    u16*  wvb = (u16*)(ws + (4u  << 20));
    u16*  wob = (u16*)(ws + (6u  << 20));
    u16*  w1b = (u16*)(ws + (8u  << 20));
    u16*  w2b = (u16*)(ws + (16u << 20));
    u16*  xn  = (u16*)(ws + (24u << 20));     // xn1 / attn_out / xn2
    u16*  q   = (u16*)(ws + (40u << 20));
    u16*  hb  = (u16*)(ws + (40u << 20));     // overlaps q (q dead by FF1)

    u16*   kbuf = (u16*)d_out;
    u16*   vbuf = (u16*)d_out + (size_t)M * D;
    float* x1   = (float*)d_out;

    cvt_all<<<12288, 256, 0, stream>>>(wq, wk, wv, wo, w1, w2,
                                       wqb, wkb, wvb, wob, w1b, w2b);

    ln_kernel<<<M / 4, 256, 0, stream>>>(x, ln1a, ln1b, xn);
    dim3 gq(M / 128, 3072 / 128);
    gemm128_qkv<<<gq, 256, 0, stream>>>(xn, wqkv, q, kbuf, vbuf, D);
    dim3 ga(2048 / 128, 64);
    attn_kernel<<<ga, 512, 0, stream>>>(q, kbuf, vbuf, mask, xn);
    dim3 g1(M / 128, D / 128);
    gemm128<true ><<<g1, 256, 0, stream>>>(xn, wob, nullptr, x, x1, M, D, D, D, 0);
    ln_kernel<<<M / 4, 256, 0, stream>>>(x1, ln2a, ln2b, xn);
    dim3 gf1(M / 128, 2048 / 128);
    dim3 gf2(M / 128, D / 128);
    gemm128<false><<<gf1, 256, 0, stream>>>(xn, w1b, b1, nullptr, hb, M, 2048, D, D, 1);
    gemm128<true ><<<gf2, 256, 0, stream>>>(hb, w2b, nullptr, x1, x1, M, D, 2048, F, 0);
    gemm128<false><<<gf1, 256, 0, stream>>>(xn, w1b + (size_t)2048 * D, b1 + 2048, nullptr, hb, M, 2048, D, D, 1);
    gemm128<true ><<<gf2, 256, 0, stream>>>(hb, w2b + 2048, b2, x1, x1, M, D, 2048, F, 0);
}

// Round 2
// 637.847 us; speedup vs baseline: 1.0591x; 1.0460x over previous
//
#include <hip/hip_runtime.h>
#include <stdint.h>

typedef unsigned short u16;
typedef __bf16 bf16x8 __attribute__((ext_vector_type(8)));
typedef float   f32x4 __attribute__((ext_vector_type(4)));
typedef u16     u16x8 __attribute__((ext_vector_type(8)));
typedef u16     u16x4 __attribute__((ext_vector_type(4)));

__device__ __forceinline__ float bf2f(u16 u) {
    union { uint32_t i; float f; } c; c.i = ((uint32_t)u) << 16; return c.f;
}
__device__ __forceinline__ u16 f2bf(float f) {
    union { float f; uint32_t i; } c; c.f = f;
    uint32_t r = c.i + 0x7FFFu + ((c.i >> 16) & 1u);   // RNE
    return (u16)(r >> 16);
}
__device__ __forceinline__ u16 f2bf_fast(float f) {    // round-half-up (2 ops)
    union { float f; uint32_t i; } c; c.f = f;
    return (u16)((c.i + 0x8000u) >> 16);
}
// packed f32x2 -> bf16x2 (RNE), one VALU op. No builtin on gfx950 (T12 recipe).
__device__ __forceinline__ uint32_t cvt_pk_bf16(float lo, float hi) {
    uint32_t r;
    asm("v_cvt_pk_bf16_f32 %0, %1, %2" : "=v"(r) : "v"(lo), "v"(hi));
    return r;
}
// async global->LDS, 16B per lane. LDS dest must be wave-uniform base + lane*16.
__device__ __forceinline__ void gload_lds16(const u16* g, u16* l) {
    __builtin_amdgcn_global_load_lds(
        (__attribute__((address_space(1))) void*)(g),
        (__attribute__((address_space(3))) void*)(l), 16, 0, 0);
}

// ---------------- fp32 -> bf16 weight conversion: ONE dispatch, 6 segments ----
// blocks [0,1024) wq | [1024,2048) wk | [2048,3072) wv | [3072,4096) wo
// blocks [4096,8192) w1 | [8192,12288) w2
__global__ __launch_bounds__(256) void cvt_all(
    const float* __restrict__ wq, const float* __restrict__ wk,
    const float* __restrict__ wv, const float* __restrict__ wo,
    const float* __restrict__ w1, const float* __restrict__ w2,
    u16* __restrict__ wqb, u16* __restrict__ wkb, u16* __restrict__ wvb,
    u16* __restrict__ wob, u16* __restrict__ w1b, u16* __restrict__ w2b)
{
    int blk = blockIdx.x;
    const float* src; u16* dst; int off;
    if      (blk < 1024)  { src = wq; dst = wqb; off = blk; }
    else if (blk < 2048)  { src = wk; dst = wkb; off = blk - 1024; }
    else if (blk < 3072)  { src = wv; dst = wvb; off = blk - 2048; }
    else if (blk < 4096)  { src = wo; dst = wob; off = blk - 3072; }
    else if (blk < 8192)  { src = w1; dst = w1b; off = blk - 4096; }
    else                  { src = w2; dst = w2b; off = blk - 8192; }
    int i = off * 1024 + threadIdx.x * 4;
    float4 v = *(const float4*)(src + i);
    u16x4 o; o[0] = f2bf(v.x); o[1] = f2bf(v.y); o[2] = f2bf(v.z); o[3] = f2bf(v.w);
    *(u16x4*)(dst + i) = o;
}

// ---------------- LayerNorm: fp32 in -> bf16 out, one wave per row (D=1024) ----
__global__ __launch_bounds__(256) void ln_kernel(
    const float* __restrict__ x, const float* __restrict__ ga,
    const float* __restrict__ be, u16* __restrict__ out)
{
    const int D = 1024;
    int row  = blockIdx.x * 4 + (threadIdx.x >> 6);
    int lane = threadIdx.x & 63;
    const float* xr = x + (size_t)row * D + lane * 16;
    float f[16];
#pragma unroll
    for (int i = 0; i < 4; ++i) *(float4*)&f[i * 4] = *(const float4*)(xr + i * 4);
    float s = 0.f, s2 = 0.f;
#pragma unroll
    for (int i = 0; i < 16; ++i) { s += f[i]; s2 += f[i] * f[i]; }
#pragma unroll
    for (int off = 1; off < 64; off <<= 1) {
        s  += __shfl_xor(s,  off, 64);
        s2 += __shfl_xor(s2, off, 64);
    }
    float mean = s * (1.0f / 1024.0f);
    float var  = s2 * (1.0f / 1024.0f) - mean * mean;
    var = var < 0.f ? 0.f : var;
    float inv = 1.0f / sqrtf(var + 1e-6f);
    float g[16], b[16];
#pragma unroll
    for (int i = 0; i < 4; ++i) {
        *(float4*)&g[i * 4] = *(const float4*)(ga + lane * 16 + i * 4);
        *(float4*)&b[i * 4] = *(const float4*)(be + lane * 16 + i * 4);
    }
    u16x8 o0, o1;
#pragma unroll
    for (int i = 0; i < 8; ++i) {
        o0[i] = f2bf(g[i]     * (f[i]     - mean) * inv + b[i]);
        o1[i] = f2bf(g[8 + i] * (f[8 + i] - mean) * inv + b[8 + i]);
    }
    u16* orow = out + (size_t)row * D + lane * 16;
    *(u16x8*)(orow)     = o0;
    *(u16x8*)(orow + 8) = o1;
}

// ------- 128x128-tile MFMA GEMM core, BK=64 (two 32-K stages per barrier) ------
// LDS: As/Bs each 128x64 as two [128][32] planes (proven conflict-free layout,
// lane-contiguous for global_load_lds). 32 KB total -> 4 blocks/CU.
__device__ __forceinline__ void gemm_core(
    const u16* __restrict__ A, const u16* __restrict__ W,
    int K, int ldw, int row_a0, int row_w0,
    u16* As, u16* Bs, f32x4 (&acc)[4][4])
{
    int tid  = threadIdx.x;
    int lane = tid & 63;
    int quad = (lane >> 4), l16 = lane & 15;
    int wave = tid >> 6;
    int wr = wave >> 1, wc = wave & 1;
    int srow = tid >> 2, scol = (tid & 3) * 8;
    const u16* a0p = A + (size_t)(row_a0 + srow) * K + scol;
    const u16* a1p = a0p + (size_t)64 * K;
    const u16* b0p = W + (size_t)(row_w0 + srow) * ldw + scol;
    const u16* b1p = b0p + (size_t)64 * ldw;
    u16* la0 = As + tid * 8;            // plane0 rows [0,64)
    u16* la1 = As + 2048 + tid * 8;     // plane0 rows [64,128)
    u16* la2 = As + 4096 + tid * 8;     // plane1 rows [0,64)
    u16* la3 = As + 6144 + tid * 8;     // plane1 rows [64,128)
    u16* lb0 = Bs + tid * 8;
    u16* lb1 = Bs + 2048 + tid * 8;
    u16* lb2 = Bs + 4096 + tid * 8;
    u16* lb3 = Bs + 6144 + tid * 8;

    for (int k0 = 0; k0 < K; k0 += 64) {
        __syncthreads();                       // prev iter's frag reads drained
        gload_lds16(a0p + k0,      la0);
        gload_lds16(a1p + k0,      la1);
        gload_lds16(a0p + k0 + 32, la2);
        gload_lds16(a1p + k0 + 32, la3);
        gload_lds16(b0p + k0,      lb0);
        gload_lds16(b1p + k0,      lb1);
        gload_lds16(b0p + k0 + 32, lb2);
        gload_lds16(b1p + k0 + 32, lb3);
        __syncthreads();                       // vmcnt(0) + barrier
#pragma unroll
        for (int h = 0; h < 2; ++h) {
            const u16* Ah = As + h * 4096;
            const u16* Bh = Bs + h * 4096;
            bf16x8 af[4], bf[4];
#pragma unroll
            for (int mt = 0; mt < 4; ++mt)
                af[mt] = *(const bf16x8*)(&Ah[(wr * 64 + mt * 16 + l16) * 32 + quad * 8]);
#pragma unroll
            for (int nt = 0; nt < 4; ++nt)
                bf[nt] = *(const bf16x8*)(&Bh[(wc * 64 + nt * 16 + l16) * 32 + quad * 8]);
#pragma unroll
            for (int mt = 0; mt < 4; ++mt)
#pragma unroll
                for (int nt = 0; nt < 4; ++nt)
                    acc[mt][nt] = __builtin_amdgcn_mfma_f32_16x16x32_bf16(
                        af[mt], bf[nt], acc[mt][nt], 0, 0, 0);
        }
    }
}

// Generic epilogue variant: C = f(A@W^T + bias) (+resid), fp32 or bf16 out.
template<bool OUTF32>
__global__ __launch_bounds__(256) void gemm128(
    const u16* __restrict__ A, const u16* __restrict__ W,
    const float* __restrict__ bias, const float* __restrict__ resid,
    void* __restrict__ Cp, int M, int N, int K, int ldw, int do_relu)
{
    __shared__ u16 As[128 * 64];
    __shared__ u16 Bs[128 * 64];
    int tid  = threadIdx.x;
    int lane = tid & 63, wave = tid >> 6;
    int quad = lane >> 4, l16 = lane & 15;
    int wr = wave >> 1, wc = wave & 1;
    const int row_a0 = blockIdx.x * 128, row_w0 = blockIdx.y * 128;
    f32x4 acc[4][4] = {};
    gemm_core(A, W, K, ldw, row_a0, row_w0, As, Bs, acc);
#pragma unroll
    for (int mt = 0; mt < 4; ++mt) {
#pragma unroll
        for (int nt = 0; nt < 4; ++nt) {
#pragma unroll
            for (int r = 0; r < 4; ++r) {
                int grow = row_a0 + wr * 64 + mt * 16 + quad * 4 + r;
                int gcol = row_w0 + wc * 64 + nt * 16 + l16;
                float vv = acc[mt][nt][r];
                if (bias)    vv += bias[gcol];
                if (do_relu) vv = vv > 0.f ? vv : 0.f;
                if (resid)   vv += resid[(size_t)grow * N + gcol];
                if (OUTF32) ((float*)Cp)[(size_t)grow * N + gcol] = vv;
                else        ((u16*)Cp)[(size_t)grow * N + gcol] = f2bf(vv);
            }
        }
    }
}

// QKV-fused variant: W is stacked [3072 x 1024]; segment -> q/k/v output.
__global__ __launch_bounds__(256) void gemm128_qkv(
    const u16* __restrict__ A, const u16* __restrict__ Wqkv,
    u16* __restrict__ qo, u16* __restrict__ ko, u16* __restrict__ vo, int K)
{
    __shared__ u16 As[128 * 64];
    __shared__ u16 Bs[128 * 64];
    int tid  = threadIdx.x;
    int lane = tid & 63, wave = tid >> 6;
    int quad = lane >> 4, l16 = lane & 15;
    int wr = wave >> 1, wc = wave & 1;
    const int row_a0 = blockIdx.x * 128, row_w0 = blockIdx.y * 128;
    f32x4 acc[4][4] = {};
    gemm_core(A, Wqkv, K, K, row_a0, row_w0, As, Bs, acc);
    int seg = row_w0 >> 10;
    u16* dst = (seg == 0) ? qo : (seg == 1) ? ko : vo;
    int col0 = row_w0 & 1023;
#pragma unroll
    for (int mt = 0; mt < 4; ++mt) {
#pragma unroll
        for (int nt = 0; nt < 4; ++nt) {
#pragma unroll
            for (int r = 0; r < 4; ++r) {
                int grow = row_a0 + wr * 64 + mt * 16 + quad * 4 + r;
                int gcol = col0 + wc * 64 + nt * 16 + l16;
                dst[(size_t)grow * 1024 + gcol] = f2bf(acc[mt][nt][r]);
            }
        }
    }
}

// -------- MFMA flash attention v3: double-buffered K/V, 1 barrier/iter --------
// Round-1 lesson: v2 cut VALUBusy 64->48 with ZERO time change, and
// SQ_LDS_BANK_CONFLICT was bit-identical (the K-read pattern was never the
// source) -> kernel is latency/sync-bound, not pipe-bound. The serial chain
// {stage -> barrier(full drain) -> QK -> softmax -> Ps -> PV -> barrier} is
// the floor. v3 (T14/T3-lite):
//  * K/V tiles double-buffered; V-loads(t+1) + K-DMA(t+1) issued at iter
//    START, so a full compute phase hides the global latency; Vt(t+1) LDS
//    write at iter END; ONE __syncthreads per iter (its implicit vmcnt(0)
//    drain is cheap: the DMA was issued a whole iteration earlier).
//  * Safety: buffer roles alternate; all reads of buffer X occur in the
//    iteration before any write to X, separated by the end-of-iter barrier.
//  * LDS stays 54,272 B: Ks1/Vt1 alias the Qs region (Qs dead after the
//    prologue register loads; first write to the alias is after the
//    post-prologue barrier).
__global__ __launch_bounds__(512, 4) void attn_kernel(
    const u16* __restrict__ Q, const u16* __restrict__ Km, const u16* __restrict__ Vm,
    const int* __restrict__ mask, u16* __restrict__ O)
{
    const int S = 2048, DM = 1024;
    const float C1 = 0.18033688f;      // 0.125 * log2(e)
    const float C0 = -11.541560f;      // -8 * log2(e)
    // u16 units: Qs 9216 | Ks 4096 | Vt 4608 | Ps 9216 -> 27136 u16 = 54272 B
    __shared__ u16 smem[27136];
    u16* Qs  = smem;                   // [128][72], prologue only
    u16* Ks1 = smem;                   // [64*64]  aliases Qs[0..4096)
    u16* Vt1 = smem + 4096;            // [64][72] aliases Qs[4096..8704)
    u16* Ks0 = smem + 9216;            // [64*64]
    u16* Vt0 = smem + 13312;           // [64][72]
    u16* Ps  = smem + 17920;           // [128][72] wave-private rows

    int qt = blockIdx.x, bh = blockIdx.y;
    int b = bh >> 4, h = bh & 15;
    int tid = threadIdx.x;
    int wave = tid >> 6, lane = tid & 63;
    int quad = lane >> 4, l16 = lane & 15;
    size_t base = (size_t)b * S;
    size_t hoff = (size_t)h * 64;

    {   // stage Q tile [128 q][64 d]
        int r = tid >> 2, c0 = (tid & 3) * 16;
        const u16* src = Q + (base + qt * 128 + r) * DM + hoff + c0;
        *(u16x8*)(&Qs[r * 72 + c0])     = *(const u16x8*)(src);
        *(u16x8*)(&Qs[r * 72 + c0 + 8]) = *(const u16x8*)(src + 8);
    }
    // K stage: LDS unit u = tid (16B units) holds K row (tid>>3), source
    // 16B-chunk (tid&7) ^ ((tid>>5)&7)  [ = (row>>2)&7 ] (kept from v2).
    const u16* ksrc = Km + (base + (tid >> 3)) * DM + hoff
                    + ((tid & 7) ^ ((tid >> 5) & 7)) * 8;
    // V stage: thread packs d-rows d0..d0+3 at key pair 2*kp.
    int kp = tid & 31, d0 = (tid >> 5) * 4;
    const u16* vsrc = Vm + (base + kp * 2) * DM + hoff + d0;
    const int* msrc = mask + b * S + 4 * l16;

    __syncthreads();
    const int q0 = wave * 16;
    bf16x8 qf0 = *(const bf16x8*)(&Qs[(q0 + l16) * 72 + quad * 8]);
    bf16x8 qf1 = *(const bf16x8*)(&Qs[(q0 + l16) * 72 + 32 + quad * 8]);
    const int swz = (l16 & 7) * 8;       // (krow>>2)&7 for krow = 4*l16+t
    const int u0  = (quad * 8) ^ swz;    // chunk offset h=0; h=1 is u0^32

    {   // prologue: stage tile 0 into Ks0/Vt0 (dedicated, no Qs alias)
        u16x4 va = *(const u16x4*)(vsrc);
        u16x4 vb = *(const u16x4*)(vsrc + DM);
        gload_lds16(ksrc, Ks0 + tid * 8);
        ksrc += 64 * DM; vsrc += 64 * DM;
#pragma unroll
        for (int i = 0; i < 4; ++i) {
            uint32_t w = (uint32_t)va[i] | ((uint32_t)vb[i] << 16);
            *(uint32_t*)(&Vt0[(d0 + i) * 72 + kp * 2]) = w;
        }
    }
    __syncthreads();   // tile0 staged; all waves past Qs reads -> alias free

    float l_r[4] = {0.f, 0.f, 0.f, 0.f};
    f32x4 o[4] = {};

    for (int it = 0; it < 32; ++it) {
        const u16* Kcur = (it & 1) ? Ks1 : Ks0;
        const u16* Vcur = (it & 1) ? Vt1 : Vt0;
        u16* Knxt = (it & 1) ? Ks0 : Ks1;
        u16* Vnxt = (it & 1) ? Vt0 : Vt1;
        const bool pfch = (it < 31);
        u16x4 va, vb;
        if (pfch) {       // issue next tile's memory FIRST (hidden under compute)
            va = *(const u16x4*)(vsrc);
            vb = *(const u16x4*)(vsrc + DM);
            gload_lds16(ksrc, Knxt + tid * 8);
            ksrc += 64 * DM; vsrc += 64 * DM;
        }
        // QK^T: tile t reads K row 4*l16+t -> score col l16 == key 4*l16+t
        f32x4 sc[4] = {};
#pragma unroll
        for (int t = 0; t < 4; ++t) {
            const u16* krp = Kcur + (4 * l16 + t) * 64;
            bf16x8 kf0 = *(const bf16x8*)(krp + u0);
            bf16x8 kf1 = *(const bf16x8*)(krp + (u0 ^ 32));
            sc[t] = __builtin_amdgcn_mfma_f32_16x16x32_bf16(qf0, kf0, sc[t], 0, 0, 0);
            sc[t] = __builtin_amdgcn_mfma_f32_16x16x32_bf16(qf1, kf1, sc[t], 0, 0, 0);
        }
        // one int4 mask load covers this lane's 4 contiguous keys
        int4 mk4 = *(const int4*)(msrc); msrc += 64;
        float c0t[4];
        c0t[0] = (mk4.x == 0) ? -1e38f : C0;
        c0t[1] = (mk4.y == 0) ? -1e38f : C0;
        c0t[2] = (mk4.z == 0) ? -1e38f : C0;
        c0t[3] = (mk4.w == 0) ? -1e38f : C0;
#pragma unroll
        for (int r = 0; r < 4; ++r) {
            float p0 = exp2f(fmaf(sc[0][r], C1, c0t[0]));
            float p1 = exp2f(fmaf(sc[1][r], C1, c0t[1]));
            float p2 = exp2f(fmaf(sc[2][r], C1, c0t[2]));
            float p3 = exp2f(fmaf(sc[3][r], C1, c0t[3]));
            l_r[r] += (p0 + p1) + (p2 + p3);
            int prow = q0 + quad * 4 + r;
            uint2 pw;
            pw.x = cvt_pk_bf16(p0, p1);
            pw.y = cvt_pk_bf16(p2, p3);
            *(uint2*)(&Ps[prow * 72 + 4 * l16]) = pw;   // contiguous keys
        }
        // PV: A = P (wave-private rows, natural key order), B = Vt
        bf16x8 pf0 = *(const bf16x8*)(&Ps[(q0 + l16) * 72 + quad * 8]);
        bf16x8 pf1 = *(const bf16x8*)(&Ps[(q0 + l16) * 72 + 32 + quad * 8]);
#pragma unroll
        for (int t = 0; t < 4; ++t) {
            bf16x8 vf0 = *(const bf16x8*)(&Vcur[(t * 16 + l16) * 72 + quad * 8]);
            bf16x8 vf1 = *(const bf16x8*)(&Vcur[(t * 16 + l16) * 72 + 32 + quad * 8]);
            o[t] = __builtin_amdgcn_mfma_f32_16x16x32_bf16(pf0, vf0, o[t], 0, 0, 0);
            o[t] = __builtin_amdgcn_mfma_f32_16x16x32_bf16(pf1, vf1, o[t], 0, 0, 0);
        }
        if (pfch) {       // V loads landed long ago; pack into next Vt buffer
#pragma unroll
            for (int i = 0; i < 4; ++i) {
                uint32_t w = (uint32_t)va[i] | ((uint32_t)vb[i] << 16);
                *(uint32_t*)(&Vnxt[(d0 + i) * 72 + kp * 2]) = w;
            }
        }
        __syncthreads();  // single barrier: publishes Vnxt/Knxt, retires Kcur/Vcur
    }
    // one 16-lane reduction per row, then epilogue
#pragma unroll
    for (int r = 0; r < 4; ++r) {
#pragma unroll
        for (int off = 1; off < 16; off <<= 1) l_r[r] += __shfl_xor(l_r[r], off, 16);
        float inv = 1.0f / l_r[r];
        u16* dst = O + (base + qt * 128 + q0 + quad * 4 + r) * DM + hoff + l16;
#pragma unroll
        for (int t = 0; t < 4; ++t) dst[t * 16] = f2bf(o[t][r] * inv);
    }
}

// -------------------------------------------------------------------------------
// Workspace budget: 72 MB (proven). ws[0..6)MB wq|wk|wv stacked; ws[6..8) wo;
// ws[8..24) w1,w2; ws[24..40) xn; ws[40..56) q; ws[40..72) hb.
// d_out doubles as k/v (bf16) then x1 (fp32).
extern "C" void kernel_launch(void* const* d_in, const int* in_sizes, int n_in,
                              void* d_out, int out_size, void* d_ws, size_t ws_size,
                              hipStream_t stream)
{
    (void)in_sizes; (void)n_in; (void)out_size; (void)ws_size;
    const float* x    = (const float*)d_in[0];
    const int*   mask = (const int*)d_in[1];
    const float* wq   = (const float*)d_in[2];
    const float* wk   = (const float*)d_in[3];
    const float* wv   = (const float*)d_in[4];
    const float* wo   = (const float*)d_in[5];
    const float* ln1a = (const float*)d_in[6];
    const float* ln1b = (const float*)d_in[7];
    const float* ln2a = (const float*)d_in[8];
    const float* ln2b = (const float*)d_in[9];
    const float* w1   = (const float*)d_in[10];
    const float* b1   = (const float*)d_in[11];
    const float* w2   = (const float*)d_in[12];
    const float* b2   = (const float*)d_in[13];

    const int M = 8192, D = 1024, F = 4096;
    char* ws = (char*)d_ws;
    u16*  wqkv = (u16*)(ws);                  // stacked 3072x1024
    u16*  wqb = wqkv;
    u16*  wkb = (u16*)(ws + (2u  << 20));
    u16*  wvb = (u16*)(ws + (4u  << 20));
    u16*  wob = (u16*)(ws + (6u  << 20));
    u16*  w1b = (u16*)(ws + (8u  << 20));
    u16*  w2b = (u16*)(ws + (16u << 20));
    u16*  xn  = (u16*)(ws + (24u << 20));     // xn1 / attn_out / xn2
    u16*  q   = (u16*)(ws + (40u << 20));
    u16*  hb  = (u16*)(ws + (40u << 20));     // overlaps q (q dead by FF1)

    u16*   kbuf = (u16*)d_out;
    u16*   vbuf = (u16*)d_out + (size_t)M * D;
    float* x1   = (float*)d_out;

    cvt_all<<<12288, 256, 0, stream>>>(wq, wk, wv, wo, w1, w2,
                                       wqb, wkb, wvb, wob, w1b, w2b);

    ln_kernel<<<M / 4, 256, 0, stream>>>(x, ln1a, ln1b, xn);
    dim3 gq(M / 128, 3072 / 128);
    gemm128_qkv<<<gq, 256, 0, stream>>>(xn, wqkv, q, kbuf, vbuf, D);
    dim3 ga(2048 / 128, 64);
    attn_kernel<<<ga, 512, 0, stream>>>(q, kbuf, vbuf, mask, xn);
    dim3 g1(M / 128, D / 128);
    gemm128<true ><<<g1, 256, 0, stream>>>(xn, wob, nullptr, x, x1, M, D, D, D, 0);
    ln_kernel<<<M / 4, 256, 0, stream>>>(x1, ln2a, ln2b, xn);
    dim3 gf1(M / 128, 2048 / 128);
    dim3 gf2(M / 128, D / 128);
    gemm128<false><<<gf1, 256, 0, stream>>>(xn, w1b, b1, nullptr, hb, M, 2048, D, D, 1);
    gemm128<true ><<<gf2, 256, 0, stream>>>(hb, w2b, nullptr, x1, x1, M, D, 2048, F, 0);
    gemm128<false><<<gf1, 256, 0, stream>>>(xn, w1b + (size_t)2048 * D, b1 + 2048, nullptr, hb, M, 2048, D, D, 1);
    gemm128<true ><<<gf2, 256, 0, stream>>>(hb, w2b + 2048, b2, x1, x1, M, D, 2048, F, 0);
}

// Round 3
// 620.735 us; speedup vs baseline: 1.0883x; 1.0276x over previous
//
#include <hip/hip_runtime.h>
#include <stdint.h>

typedef unsigned short u16;
typedef __bf16 bf16x8 __attribute__((ext_vector_type(8)));
typedef float   f32x4 __attribute__((ext_vector_type(4)));
typedef u16     u16x8 __attribute__((ext_vector_type(8)));
typedef u16     u16x4 __attribute__((ext_vector_type(4)));

__device__ __forceinline__ float bf2f(u16 u) {
    union { uint32_t i; float f; } c; c.i = ((uint32_t)u) << 16; return c.f;
}
__device__ __forceinline__ u16 f2bf(float f) {
    union { float f; uint32_t i; } c; c.f = f;
    uint32_t r = c.i + 0x7FFFu + ((c.i >> 16) & 1u);   // RNE
    return (u16)(r >> 16);
}
__device__ __forceinline__ u16 f2bf_fast(float f) {    // round-half-up (2 ops)
    union { float f; uint32_t i; } c; c.f = f;
    return (u16)((c.i + 0x8000u) >> 16);
}
// packed f32x2 -> bf16x2 (RNE), one VALU op. No builtin on gfx950 (T12 recipe).
__device__ __forceinline__ uint32_t cvt_pk_bf16(float lo, float hi) {
    uint32_t r;
    asm("v_cvt_pk_bf16_f32 %0, %1, %2" : "=v"(r) : "v"(lo), "v"(hi));
    return r;
}
// async global->LDS, 16B per lane. LDS dest must be wave-uniform base + lane*16.
__device__ __forceinline__ void gload_lds16(const u16* g, u16* l) {
    __builtin_amdgcn_global_load_lds(
        (__attribute__((address_space(1))) void*)(g),
        (__attribute__((address_space(3))) void*)(l), 16, 0, 0);
}

// ---------------- fp32 -> bf16 weight conversion: ONE dispatch, 6 segments ----
// blocks [0,1024) wq | [1024,2048) wk | [2048,3072) wv | [3072,4096) wo
// blocks [4096,8192) w1 | [8192,12288) w2
__global__ __launch_bounds__(256) void cvt_all(
    const float* __restrict__ wq, const float* __restrict__ wk,
    const float* __restrict__ wv, const float* __restrict__ wo,
    const float* __restrict__ w1, const float* __restrict__ w2,
    u16* __restrict__ wqb, u16* __restrict__ wkb, u16* __restrict__ wvb,
    u16* __restrict__ wob, u16* __restrict__ w1b, u16* __restrict__ w2b)
{
    int blk = blockIdx.x;
    const float* src; u16* dst; int off;
    if      (blk < 1024)  { src = wq; dst = wqb; off = blk; }
    else if (blk < 2048)  { src = wk; dst = wkb; off = blk - 1024; }
    else if (blk < 3072)  { src = wv; dst = wvb; off = blk - 2048; }
    else if (blk < 4096)  { src = wo; dst = wob; off = blk - 3072; }
    else if (blk < 8192)  { src = w1; dst = w1b; off = blk - 4096; }
    else                  { src = w2; dst = w2b; off = blk - 8192; }
    int i = off * 1024 + threadIdx.x * 4;
    float4 v = *(const float4*)(src + i);
    u16x4 o; o[0] = f2bf(v.x); o[1] = f2bf(v.y); o[2] = f2bf(v.z); o[3] = f2bf(v.w);
    *(u16x4*)(dst + i) = o;
}

// ---------------- LayerNorm: fp32 in -> bf16 out, one wave per row (D=1024) ----
__global__ __launch_bounds__(256) void ln_kernel(
    const float* __restrict__ x, const float* __restrict__ ga,
    const float* __restrict__ be, u16* __restrict__ out)
{
    const int D = 1024;
    int row  = blockIdx.x * 4 + (threadIdx.x >> 6);
    int lane = threadIdx.x & 63;
    const float* xr = x + (size_t)row * D + lane * 16;
    float f[16];
#pragma unroll
    for (int i = 0; i < 4; ++i) *(float4*)&f[i * 4] = *(const float4*)(xr + i * 4);
    float s = 0.f, s2 = 0.f;
#pragma unroll
    for (int i = 0; i < 16; ++i) { s += f[i]; s2 += f[i] * f[i]; }
#pragma unroll
    for (int off = 1; off < 64; off <<= 1) {
        s  += __shfl_xor(s,  off, 64);
        s2 += __shfl_xor(s2, off, 64);
    }
    float mean = s * (1.0f / 1024.0f);
    float var  = s2 * (1.0f / 1024.0f) - mean * mean;
    var = var < 0.f ? 0.f : var;
    float inv = 1.0f / sqrtf(var + 1e-6f);
    float g[16], b[16];
#pragma unroll
    for (int i = 0; i < 4; ++i) {
        *(float4*)&g[i * 4] = *(const float4*)(ga + lane * 16 + i * 4);
        *(float4*)&b[i * 4] = *(const float4*)(be + lane * 16 + i * 4);
    }
    u16x8 o0, o1;
#pragma unroll
    for (int i = 0; i < 8; ++i) {
        o0[i] = f2bf(g[i]     * (f[i]     - mean) * inv + b[i]);
        o1[i] = f2bf(g[8 + i] * (f[8 + i] - mean) * inv + b[8 + i]);
    }
    u16* orow = out + (size_t)row * D + lane * 16;
    *(u16x8*)(orow)     = o0;
    *(u16x8*)(orow + 8) = o1;
}

// ------- 128x128-tile MFMA GEMM core, BK=64 (two 32-K stages per barrier) ------
// LDS: As/Bs each 128x64 as two [128][32] planes (proven conflict-free layout,
// lane-contiguous for global_load_lds). 32 KB total -> 4 blocks/CU.
__device__ __forceinline__ void gemm_core(
    const u16* __restrict__ A, const u16* __restrict__ W,
    int K, int ldw, int row_a0, int row_w0,
    u16* As, u16* Bs, f32x4 (&acc)[4][4])
{
    int tid  = threadIdx.x;
    int lane = tid & 63;
    int quad = (lane >> 4), l16 = lane & 15;
    int wave = tid >> 6;
    int wr = wave >> 1, wc = wave & 1;
    int srow = tid >> 2, scol = (tid & 3) * 8;
    const u16* a0p = A + (size_t)(row_a0 + srow) * K + scol;
    const u16* a1p = a0p + (size_t)64 * K;
    const u16* b0p = W + (size_t)(row_w0 + srow) * ldw + scol;
    const u16* b1p = b0p + (size_t)64 * ldw;
    u16* la0 = As + tid * 8;            // plane0 rows [0,64)
    u16* la1 = As + 2048 + tid * 8;     // plane0 rows [64,128)
    u16* la2 = As + 4096 + tid * 8;     // plane1 rows [0,64)
    u16* la3 = As + 6144 + tid * 8;     // plane1 rows [64,128)
    u16* lb0 = Bs + tid * 8;
    u16* lb1 = Bs + 2048 + tid * 8;
    u16* lb2 = Bs + 4096 + tid * 8;
    u16* lb3 = Bs + 6144 + tid * 8;

    for (int k0 = 0; k0 < K; k0 += 64) {
        __syncthreads();                       // prev iter's frag reads drained
        gload_lds16(a0p + k0,      la0);
        gload_lds16(a1p + k0,      la1);
        gload_lds16(a0p + k0 + 32, la2);
        gload_lds16(a1p + k0 + 32, la3);
        gload_lds16(b0p + k0,      lb0);
        gload_lds16(b1p + k0,      lb1);
        gload_lds16(b0p + k0 + 32, lb2);
        gload_lds16(b1p + k0 + 32, lb3);
        __syncthreads();                       // vmcnt(0) + barrier
#pragma unroll
        for (int h = 0; h < 2; ++h) {
            const u16* Ah = As + h * 4096;
            const u16* Bh = Bs + h * 4096;
            bf16x8 af[4], bf[4];
#pragma unroll
            for (int mt = 0; mt < 4; ++mt)
                af[mt] = *(const bf16x8*)(&Ah[(wr * 64 + mt * 16 + l16) * 32 + quad * 8]);
#pragma unroll
            for (int nt = 0; nt < 4; ++nt)
                bf[nt] = *(const bf16x8*)(&Bh[(wc * 64 + nt * 16 + l16) * 32 + quad * 8]);
#pragma unroll
            for (int mt = 0; mt < 4; ++mt)
#pragma unroll
                for (int nt = 0; nt < 4; ++nt)
                    acc[mt][nt] = __builtin_amdgcn_mfma_f32_16x16x32_bf16(
                        af[mt], bf[nt], acc[mt][nt], 0, 0, 0);
        }
    }
}

// Generic epilogue variant: C = f(A@W^T + bias) (+resid), fp32 or bf16 out.
template<bool OUTF32>
__global__ __launch_bounds__(256) void gemm128(
    const u16* __restrict__ A, const u16* __restrict__ W,
    const float* __restrict__ bias, const float* __restrict__ resid,
    void* __restrict__ Cp, int M, int N, int K, int ldw, int do_relu)
{
    __shared__ u16 As[128 * 64];
    __shared__ u16 Bs[128 * 64];
    int tid  = threadIdx.x;
    int lane = tid & 63, wave = tid >> 6;
    int quad = lane >> 4, l16 = lane & 15;
    int wr = wave >> 1, wc = wave & 1;
    const int row_a0 = blockIdx.x * 128, row_w0 = blockIdx.y * 128;
    f32x4 acc[4][4] = {};
    gemm_core(A, W, K, ldw, row_a0, row_w0, As, Bs, acc);
#pragma unroll
    for (int mt = 0; mt < 4; ++mt) {
#pragma unroll
        for (int nt = 0; nt < 4; ++nt) {
#pragma unroll
            for (int r = 0; r < 4; ++r) {
                int grow = row_a0 + wr * 64 + mt * 16 + quad * 4 + r;
                int gcol = row_w0 + wc * 64 + nt * 16 + l16;
                float vv = acc[mt][nt][r];
                if (bias)    vv += bias[gcol];
                if (do_relu) vv = vv > 0.f ? vv : 0.f;
                if (resid)   vv += resid[(size_t)grow * N + gcol];
                if (OUTF32) ((float*)Cp)[(size_t)grow * N + gcol] = vv;
                else        ((u16*)Cp)[(size_t)grow * N + gcol] = f2bf(vv);
            }
        }
    }
}

// QKV-fused variant: W is stacked [3072 x 1024]; segment -> q/k/v output.
__global__ __launch_bounds__(256) void gemm128_qkv(
    const u16* __restrict__ A, const u16* __restrict__ Wqkv,
    u16* __restrict__ qo, u16* __restrict__ ko, u16* __restrict__ vo, int K)
{
    __shared__ u16 As[128 * 64];
    __shared__ u16 Bs[128 * 64];
    int tid  = threadIdx.x;
    int lane = tid & 63, wave = tid >> 6;
    int quad = lane >> 4, l16 = lane & 15;
    int wr = wave >> 1, wc = wave & 1;
    const int row_a0 = blockIdx.x * 128, row_w0 = blockIdx.y * 128;
    f32x4 acc[4][4] = {};
    gemm_core(A, Wqkv, K, K, row_a0, row_w0, As, Bs, acc);
    int seg = row_w0 >> 10;
    u16* dst = (seg == 0) ? qo : (seg == 1) ? ko : vo;
    int col0 = row_w0 & 1023;
#pragma unroll
    for (int mt = 0; mt < 4; ++mt) {
#pragma unroll
        for (int nt = 0; nt < 4; ++nt) {
#pragma unroll
            for (int r = 0; r < 4; ++r) {
                int grow = row_a0 + wr * 64 + mt * 16 + quad * 4 + r;
                int gcol = col0 + wc * 64 + nt * 16 + l16;
                dst[(size_t)grow * 1024 + gcol] = f2bf(acc[mt][nt][r]);
            }
        }
    }
}

// -------- MFMA flash attention v4: 32 q-rows/wave, 256-q blocks ---------------
// Round-2 accounting: kernel is LDS-BANDWIDTH-bound (~352KB/CU-iter vs 128B/cy
// peak = 50-75% busy; VALU/MFMA per-SIMD <20%). SQ_LDS_BANK_CONFLICT=1.894e7 is
// STRUCTURAL (18 b128/wave-iter x 4 extra cy x 262k wave-iters — invariant
// across v1/v2/v3 because b128 count was invariant). The redundancy: all 8
// waves read IDENTICAL K/Vt fragments (B-operands depend on lane only).
// v4: each wave owns 32 q-rows (2 q-subtiles) -> kf/vf loaded once feed TWO
// q-subtiles -> K/V LDS reads per q-row halve (1.38 -> 0.77 KB/q-row).
// Grid 8x64 = 512 blocks = exactly 2/CU in ONE pass. LDS 71,680B (Qs aliases
// Ps; Qs dead before first Ps write, qf ds_reads drained at prologue barrier).
// __launch_bounds__(512,4) pins VGPR<=128 to hold 2 blocks/CU.
__global__ __launch_bounds__(512, 4) void attn_kernel(
    const u16* __restrict__ Q, const u16* __restrict__ Km, const u16* __restrict__ Vm,
    const int* __restrict__ mask, u16* __restrict__ O)
{
    const int S = 2048, DM = 1024;
    const float C1 = 0.18033688f;      // 0.125 * log2(e)
    const float C0 = -11.541560f;      // -8 * log2(e)
    // u16 units: Ks0 4096 | Ks1 4096 | Vt0 4608 | Vt1 4608 | Ps 18432 = 35840
    __shared__ u16 smem[35840];        // 71,680 B -> 2 blocks/CU
    u16* Ks0 = smem;                   // [64*64] swizzled 16B chunks
    u16* Ks1 = smem + 4096;
    u16* Vt0 = smem + 8192;            // [64][72]
    u16* Vt1 = smem + 12800;
    u16* Ps  = smem + 17408;           // [256][72] wave-private rows
    u16* Qs  = smem + 17408;           // alias: Qs dead before Ps written

    int qt = blockIdx.x, bh = blockIdx.y;
    int b = bh >> 4, h = bh & 15;
    int tid = threadIdx.x;
    int wave = tid >> 6, lane = tid & 63;
    int quad = lane >> 4, l16 = lane & 15;
    size_t base = (size_t)b * S;
    size_t hoff = (size_t)h * 64;

    {   // stage Q tile [256 q][64 d]: 32 u16 per thread
        int r = tid >> 1, c0 = (tid & 1) * 32;
        const u16* src = Q + (base + qt * 256 + r) * DM + hoff + c0;
        u16* dq = Qs + r * 72 + c0;
        *(u16x8*)(dq)      = *(const u16x8*)(src);
        *(u16x8*)(dq + 8)  = *(const u16x8*)(src + 8);
        *(u16x8*)(dq + 16) = *(const u16x8*)(src + 16);
        *(u16x8*)(dq + 24) = *(const u16x8*)(src + 24);
    }
    // K stage: LDS unit u = tid (16B units) holds K row (tid>>3), source
    // 16B-chunk (tid&7) ^ ((tid>>5)&7)  [ = (row>>2)&7 ].
    const u16* ksrc = Km + (base + (tid >> 3)) * DM + hoff
                    + ((tid & 7) ^ ((tid >> 5) & 7)) * 8;
    // V stage: thread packs d-rows d0..d0+3 at key pair 2*kp.
    int kp = tid & 31, d0 = (tid >> 5) * 4;    // tid>>5 in 0..15 -> d0 0..60
    const u16* vsrc = Vm + (base + kp * 2) * DM + hoff + d0;
    const int* msrc = mask + b * S + 4 * l16;

    __syncthreads();
    const int q0 = wave * 32;
    bf16x8 qf00 = *(const bf16x8*)(&Qs[(q0 + l16) * 72 + quad * 8]);
    bf16x8 qf01 = *(const bf16x8*)(&Qs[(q0 + l16) * 72 + 32 + quad * 8]);
    bf16x8 qf10 = *(const bf16x8*)(&Qs[(q0 + 16 + l16) * 72 + quad * 8]);
    bf16x8 qf11 = *(const bf16x8*)(&Qs[(q0 + 16 + l16) * 72 + 32 + quad * 8]);
    const int swz = (l16 & 7) * 8;       // (krow>>2)&7 for krow = 4*l16+t
    const int u0  = (quad * 8) ^ swz;    // chunk offset half0; half1 = u0^32

    {   // prologue: stage tile 0 into Ks0/Vt0 (dedicated, no alias)
        u16x4 va = *(const u16x4*)(vsrc);
        u16x4 vb = *(const u16x4*)(vsrc + DM);
        gload_lds16(ksrc, Ks0 + tid * 8);
        ksrc += 64 * DM; vsrc += 64 * DM;
#pragma unroll
        for (int i = 0; i < 4; ++i) {
            uint32_t w = (uint32_t)va[i] | ((uint32_t)vb[i] << 16);
            *(uint32_t*)(&Vt0[(d0 + i) * 72 + kp * 2]) = w;
        }
    }
    __syncthreads();   // tile0 staged; all qf reads drained -> Ps alias free

    float l0[4] = {0.f, 0.f, 0.f, 0.f};
    float l1[4] = {0.f, 0.f, 0.f, 0.f};
    f32x4 o0[4] = {}, o1[4] = {};

    for (int it = 0; it < 32; ++it) {
        const u16* Kcur = (it & 1) ? Ks1 : Ks0;
        const u16* Vcur = (it & 1) ? Vt1 : Vt0;
        u16* Knxt = (it & 1) ? Ks0 : Ks1;
        u16* Vnxt = (it & 1) ? Vt0 : Vt1;
        const bool pfch = (it < 31);
        u16x4 va, vb;
        if (pfch) {       // issue next tile's memory FIRST (hidden under compute)
            va = *(const u16x4*)(vsrc);
            vb = *(const u16x4*)(vsrc + DM);
            gload_lds16(ksrc, Knxt + tid * 8);
            ksrc += 64 * DM; vsrc += 64 * DM;
        }
        // QK^T: kf loaded once per t, feeds BOTH q-subtiles (the redundancy cut)
        f32x4 s0[4] = {}, s1[4] = {};
#pragma unroll
        for (int t = 0; t < 4; ++t) {
            const u16* krp = Kcur + (4 * l16 + t) * 64;
            bf16x8 kf0 = *(const bf16x8*)(krp + u0);
            bf16x8 kf1 = *(const bf16x8*)(krp + (u0 ^ 32));
            s0[t] = __builtin_amdgcn_mfma_f32_16x16x32_bf16(qf00, kf0, s0[t], 0, 0, 0);
            s0[t] = __builtin_amdgcn_mfma_f32_16x16x32_bf16(qf01, kf1, s0[t], 0, 0, 0);
            s1[t] = __builtin_amdgcn_mfma_f32_16x16x32_bf16(qf10, kf0, s1[t], 0, 0, 0);
            s1[t] = __builtin_amdgcn_mfma_f32_16x16x32_bf16(qf11, kf1, s1[t], 0, 0, 0);
        }
        // one int4 mask load covers this lane's 4 contiguous keys (both subtiles)
        int4 mk4 = *(const int4*)(msrc); msrc += 64;
        float c0t[4];
        c0t[0] = (mk4.x == 0) ? -1e38f : C0;
        c0t[1] = (mk4.y == 0) ? -1e38f : C0;
        c0t[2] = (mk4.z == 0) ? -1e38f : C0;
        c0t[3] = (mk4.w == 0) ? -1e38f : C0;
#pragma unroll
        for (int r = 0; r < 4; ++r) {
            float p0 = exp2f(fmaf(s0[0][r], C1, c0t[0]));
            float p1 = exp2f(fmaf(s0[1][r], C1, c0t[1]));
            float p2 = exp2f(fmaf(s0[2][r], C1, c0t[2]));
            float p3 = exp2f(fmaf(s0[3][r], C1, c0t[3]));
            l0[r] += (p0 + p1) + (p2 + p3);
            uint2 pw;
            pw.x = cvt_pk_bf16(p0, p1);
            pw.y = cvt_pk_bf16(p2, p3);
            *(uint2*)(&Ps[(q0 + quad * 4 + r) * 72 + 4 * l16]) = pw;
        }
#pragma unroll
        for (int r = 0; r < 4; ++r) {
            float p0 = exp2f(fmaf(s1[0][r], C1, c0t[0]));
            float p1 = exp2f(fmaf(s1[1][r], C1, c0t[1]));
            float p2 = exp2f(fmaf(s1[2][r], C1, c0t[2]));
            float p3 = exp2f(fmaf(s1[3][r], C1, c0t[3]));
            l1[r] += (p0 + p1) + (p2 + p3);
            uint2 pw;
            pw.x = cvt_pk_bf16(p0, p1);
            pw.y = cvt_pk_bf16(p2, p3);
            *(uint2*)(&Ps[(q0 + 16 + quad * 4 + r) * 72 + 4 * l16]) = pw;
        }
        // PV: vf loaded once per t, feeds BOTH q-subtiles
        bf16x8 pf00 = *(const bf16x8*)(&Ps[(q0 + l16) * 72 + quad * 8]);
        bf16x8 pf01 = *(const bf16x8*)(&Ps[(q0 + l16) * 72 + 32 + quad * 8]);
        bf16x8 pf10 = *(const bf16x8*)(&Ps[(q0 + 16 + l16) * 72 + quad * 8]);
        bf16x8 pf11 = *(const bf16x8*)(&Ps[(q0 + 16 + l16) * 72 + 32 + quad * 8]);
#pragma unroll
        for (int t = 0; t < 4; ++t) {
            bf16x8 vf0 = *(const bf16x8*)(&Vcur[(t * 16 + l16) * 72 + quad * 8]);
            bf16x8 vf1 = *(const bf16x8*)(&Vcur[(t * 16 + l16) * 72 + 32 + quad * 8]);
            o0[t] = __builtin_amdgcn_mfma_f32_16x16x32_bf16(pf00, vf0, o0[t], 0, 0, 0);
            o0[t] = __builtin_amdgcn_mfma_f32_16x16x32_bf16(pf01, vf1, o0[t], 0, 0, 0);
            o1[t] = __builtin_amdgcn_mfma_f32_16x16x32_bf16(pf10, vf0, o1[t], 0, 0, 0);
            o1[t] = __builtin_amdgcn_mfma_f32_16x16x32_bf16(pf11, vf1, o1[t], 0, 0, 0);
        }
        if (pfch) {       // V loads landed long ago; pack into next Vt buffer
#pragma unroll
            for (int i = 0; i < 4; ++i) {
                uint32_t w = (uint32_t)va[i] | ((uint32_t)vb[i] << 16);
                *(uint32_t*)(&Vnxt[(d0 + i) * 72 + kp * 2]) = w;
            }
        }
        __syncthreads();  // single barrier: publishes Vnxt/Knxt, retires Kcur/Vcur
    }
    // one 16-lane reduction per row, then epilogue (both subtiles)
#pragma unroll
    for (int r = 0; r < 4; ++r) {
#pragma unroll
        for (int off = 1; off < 16; off <<= 1) {
            l0[r] += __shfl_xor(l0[r], off, 16);
            l1[r] += __shfl_xor(l1[r], off, 16);
        }
        float i0 = 1.0f / l0[r];
        float i1 = 1.0f / l1[r];
        u16* dst0 = O + (base + qt * 256 + q0 + quad * 4 + r) * DM + hoff + l16;
        u16* dst1 = dst0 + (size_t)16 * DM;
#pragma unroll
        for (int t = 0; t < 4; ++t) {
            dst0[t * 16] = f2bf(o0[t][r] * i0);
            dst1[t * 16] = f2bf(o1[t][r] * i1);
        }
    }
}

// -------------------------------------------------------------------------------
// Workspace budget: 72 MB (proven). ws[0..6)MB wq|wk|wv stacked; ws[6..8) wo;
// ws[8..24) w1,w2; ws[24..40) xn; ws[40..56) q; ws[40..72) hb.
// d_out doubles as k/v (bf16) then x1 (fp32).
extern "C" void kernel_launch(void* const* d_in, const int* in_sizes, int n_in,
                              void* d_out, int out_size, void* d_ws, size_t ws_size,
                              hipStream_t stream)
{
    (void)in_sizes; (void)n_in; (void)out_size; (void)ws_size;
    const float* x    = (const float*)d_in[0];
    const int*   mask = (const int*)d_in[1];
    const float* wq   = (const float*)d_in[2];
    const float* wk   = (const float*)d_in[3];
    const float* wv   = (const float*)d_in[4];
    const float* wo   = (const float*)d_in[5];
    const float* ln1a = (const float*)d_in[6];
    const float* ln1b = (const float*)d_in[7];
    const float* ln2a = (const float*)d_in[8];
    const float* ln2b = (const float*)d_in[9];
    const float* w1   = (const float*)d_in[10];
    const float* b1   = (const float*)d_in[11];
    const float* w2   = (const float*)d_in[12];
    const float* b2   = (const float*)d_in[13];

    const int M = 8192, D = 1024, F = 4096;
    char* ws = (char*)d_ws;
    u16*  wqkv = (u16*)(ws);                  // stacked 3072x1024
    u16*  wqb = wqkv;
    u16*  wkb = (u16*)(ws + (2u  << 20));
    u16*  wvb = (u16*)(ws + (4u  << 20));
    u16*  wob = (u16*)(ws + (6u  << 20));
    u16*  w1b = (u16*)(ws + (8u  << 20));
    u16*  w2b = (u16*)(ws + (16u << 20));
    u16*  xn  = (u16*)(ws + (24u << 20));     // xn1 / attn_out / xn2
    u16*  q   = (u16*)(ws + (40u << 20));
    u16*  hb  = (u16*)(ws + (40u << 20));     // overlaps q (q dead by FF1)

    u16*   kbuf = (u16*)d_out;
    u16*   vbuf = (u16*)d_out + (size_t)M * D;
    float* x1   = (float*)d_out;

    cvt_all<<<12288, 256, 0, stream>>>(wq, wk, wv, wo, w1, w2,
                                       wqb, wkb, wvb, wob, w1b, w2b);

    ln_kernel<<<M / 4, 256, 0, stream>>>(x, ln1a, ln1b, xn);
    dim3 gq(M / 128, 3072 / 128);
    gemm128_qkv<<<gq, 256, 0, stream>>>(xn, wqkv, q, kbuf, vbuf, D);
    dim3 ga(2048 / 256, 64);
    attn_kernel<<<ga, 512, 0, stream>>>(q, kbuf, vbuf, mask, xn);
    dim3 g1(M / 128, D / 128);
    gemm128<true ><<<g1, 256, 0, stream>>>(xn, wob, nullptr, x, x1, M, D, D, D, 0);
    ln_kernel<<<M / 4, 256, 0, stream>>>(x1, ln2a, ln2b, xn);
    dim3 gf1(M / 128, 2048 / 128);
    dim3 gf2(M / 128, D / 128);
    gemm128<false><<<gf1, 256, 0, stream>>>(xn, w1b, b1, nullptr, hb, M, 2048, D, D, 1);
    gemm128<true ><<<gf2, 256, 0, stream>>>(hb, w2b, nullptr, x1, x1, M, D, 2048, F, 0);
    gemm128<false><<<gf1, 256, 0, stream>>>(xn, w1b + (size_t)2048 * D, b1 + 2048, nullptr, hb, M, 2048, D, D, 1);
    gemm128<true ><<<gf2, 256, 0, stream>>>(hb, w2b + 2048, b2, x1, x1, M, D, 2048, F, 0);
}

// Round 4
// 587.260 us; speedup vs baseline: 1.1503x; 1.0570x over previous
//
#include <hip/hip_runtime.h>
#include <stdint.h>

typedef unsigned short u16;
typedef __bf16 bf16x8 __attribute__((ext_vector_type(8)));
typedef float   f32x4 __attribute__((ext_vector_type(4)));
typedef u16     u16x8 __attribute__((ext_vector_type(8)));
typedef u16     u16x4 __attribute__((ext_vector_type(4)));

__device__ __forceinline__ u16 f2bf(float f) {
    union { float f; uint32_t i; } c; c.f = f;
    uint32_t r = c.i + 0x7FFFu + ((c.i >> 16) & 1u);   // RNE
    return (u16)(r >> 16);
}
// packed f32x2 -> bf16x2 (RNE), one VALU op. No builtin on gfx950 (T12 recipe).
__device__ __forceinline__ uint32_t cvt_pk_bf16(float lo, float hi) {
    uint32_t r;
    asm("v_cvt_pk_bf16_f32 %0, %1, %2" : "=v"(r) : "v"(lo), "v"(hi));
    return r;
}
// async global->LDS, 16B per lane. LDS dest must be wave-uniform base + lane*16.
__device__ __forceinline__ void gload_lds16(const u16* g, u16* l) {
    __builtin_amdgcn_global_load_lds(
        (__attribute__((address_space(1))) void*)(g),
        (__attribute__((address_space(3))) void*)(l), 16, 0, 0);
}

// ---------------- fp32 -> bf16 weight conversion: ONE dispatch, 6 segments ----
__global__ __launch_bounds__(256) void cvt_all(
    const float* __restrict__ wq, const float* __restrict__ wk,
    const float* __restrict__ wv, const float* __restrict__ wo,
    const float* __restrict__ w1, const float* __restrict__ w2,
    u16* __restrict__ wqb, u16* __restrict__ wkb, u16* __restrict__ wvb,
    u16* __restrict__ wob, u16* __restrict__ w1b, u16* __restrict__ w2b)
{
    int blk = blockIdx.x;
    const float* src; u16* dst; int off;
    if      (blk < 1024)  { src = wq; dst = wqb; off = blk; }
    else if (blk < 2048)  { src = wk; dst = wkb; off = blk - 1024; }
    else if (blk < 3072)  { src = wv; dst = wvb; off = blk - 2048; }
    else if (blk < 4096)  { src = wo; dst = wob; off = blk - 3072; }
    else if (blk < 8192)  { src = w1; dst = w1b; off = blk - 4096; }
    else                  { src = w2; dst = w2b; off = blk - 8192; }
    int i = off * 1024 + threadIdx.x * 4;
    float4 v = *(const float4*)(src + i);
    u16x4 o; o[0] = f2bf(v.x); o[1] = f2bf(v.y); o[2] = f2bf(v.z); o[3] = f2bf(v.w);
    *(u16x4*)(dst + i) = o;
}

// ---------------- LayerNorm: fp32 in -> bf16 out, one wave per row (D=1024) ----
__global__ __launch_bounds__(256) void ln_kernel(
    const float* __restrict__ x, const float* __restrict__ ga,
    const float* __restrict__ be, u16* __restrict__ out)
{
    const int D = 1024;
    int row  = blockIdx.x * 4 + (threadIdx.x >> 6);
    int lane = threadIdx.x & 63;
    const float* xr = x + (size_t)row * D + lane * 16;
    float f[16];
#pragma unroll
    for (int i = 0; i < 4; ++i) *(float4*)&f[i * 4] = *(const float4*)(xr + i * 4);
    float s = 0.f, s2 = 0.f;
#pragma unroll
    for (int i = 0; i < 16; ++i) { s += f[i]; s2 += f[i] * f[i]; }
#pragma unroll
    for (int off = 1; off < 64; off <<= 1) {
        s  += __shfl_xor(s,  off, 64);
        s2 += __shfl_xor(s2, off, 64);
    }
    float mean = s * (1.0f / 1024.0f);
    float var  = s2 * (1.0f / 1024.0f) - mean * mean;
    var = var < 0.f ? 0.f : var;
    float inv = 1.0f / sqrtf(var + 1e-6f);
    float g[16], b[16];
#pragma unroll
    for (int i = 0; i < 4; ++i) {
        *(float4*)&g[i * 4] = *(const float4*)(ga + lane * 16 + i * 4);
        *(float4*)&b[i * 4] = *(const float4*)(be + lane * 16 + i * 4);
    }
    u16x8 o0, o1;
#pragma unroll
    for (int i = 0; i < 8; ++i) {
        o0[i] = f2bf(g[i]     * (f[i]     - mean) * inv + b[i]);
        o1[i] = f2bf(g[8 + i] * (f[8 + i] - mean) * inv + b[8 + i]);
    }
    u16* orow = out + (size_t)row * D + lane * 16;
    *(u16x8*)(orow)     = o0;
    *(u16x8*)(orow + 8) = o1;
}

// ------- 128x256-tile 2-phase dbuf MFMA GEMM core (512 thr, 8 waves 2Mx4N) ----
// Round-3 accounting: GEMM aggregate ~445 TF; the 2-barrier-per-K-step drain
// stall (no prefetch overlap) + 2-blocks/CU grids on N=1024 shapes were the
// deficits. This core applies the session-proven attn-v3 pattern: double-
// buffered LDS, next-tile DMA issued at iteration top (hidden under 32 MFMA),
// ONE barrier per K-step (implicit vmcnt(0) drains a DMA issued a full
// compute-phase earlier). Safety: reads of buffer X retire at the barrier one
// iteration before X is DMA-overwritten. LDS layout: per-tile k-planes
// [rows][32] (row stride 64B, af/bf reads 2-way-free; lane-linear DMA dest).
// LDS 96 KB = 1 block/CU; BN=256 makes all grids whole full-GPU rounds.
__device__ __forceinline__ void gemm256_core(
    const u16* __restrict__ A, const u16* __restrict__ W,
    int K, int ldw, int row_a0, int row_w0,
    u16* smem, f32x4 (&acc)[4][4])
{
    int tid  = threadIdx.x;
    int lane = tid & 63;
    int quad = lane >> 4, l16 = lane & 15;
    int wave = tid >> 6;
    int wm = wave >> 2, wn = wave & 3;         // 2 x 4 wave grid

    // staging sources: thread t covers row t>>2, 16B chunk (t&3)*8
    const u16* as0 = A + (size_t)(row_a0 + (tid >> 2)) * K   + (tid & 3) * 8;
    const u16* bs0 = W + (size_t)(row_w0 + (tid >> 2)) * ldw + (tid & 3) * 8;
    const u16* bs1 = bs0 + (size_t)128 * ldw;
    // LDS offsets (u16 elems), per 24576-elem (48KB) buffer:
    //   A p0 [128][32] @0 | A p1 @4096 | B p0 [256][32] @8192 | B p1 @16384
    u16* d_a0 = smem + tid * 8;                // A plane0 rows 0..127
    u16* d_a1 = smem + 4096  + tid * 8;        // A plane1
    u16* d_b00 = smem + 8192  + tid * 8;       // B p0 rows 0..127
    u16* d_b01 = smem + 12288 + tid * 8;       // B p0 rows 128..255
    u16* d_b10 = smem + 16384 + tid * 8;       // B p1 rows 0..127
    u16* d_b11 = smem + 20480 + tid * 8;       // B p1 rows 128..255

    const int nk = K >> 6;
    // prologue: stage tile 0 into buf0
    gload_lds16(as0,      d_a0);
    gload_lds16(as0 + 32, d_a1);
    gload_lds16(bs0,      d_b00);
    gload_lds16(bs0 + 32, d_b10);
    gload_lds16(bs1,      d_b01);
    gload_lds16(bs1 + 32, d_b11);
    __syncthreads();                            // vmcnt(0): tile0 ready

    const int aoff = (wm * 64 + l16) * 32 + quad * 8;   // + mt*16*32
    const int boff = (wn * 64 + l16) * 32 + quad * 8;   // + nt*16*32

    for (int t = 0; t < nk; ++t) {
        const int cb = (t & 1) * 24576;
        if (t + 1 < nk) {                       // issue next tile's DMA FIRST
            const int nb = ((t + 1) & 1) * 24576;
            const int k0 = (t + 1) * 64;
            gload_lds16(as0 + k0,      d_a0  + nb);
            gload_lds16(as0 + k0 + 32, d_a1  + nb);
            gload_lds16(bs0 + k0,      d_b00 + nb);
            gload_lds16(bs0 + k0 + 32, d_b10 + nb);
            gload_lds16(bs1 + k0,      d_b01 + nb);
            gload_lds16(bs1 + k0 + 32, d_b11 + nb);
        }
#pragma unroll
        for (int h = 0; h < 2; ++h) {
            const u16* Ah = smem + cb + h * 4096;
            const u16* Bh = smem + cb + 8192 + h * 8192;
            bf16x8 af[4], bf[4];
#pragma unroll
            for (int mt = 0; mt < 4; ++mt)
                af[mt] = *(const bf16x8*)(&Ah[aoff + mt * 512]);
#pragma unroll
            for (int nt = 0; nt < 4; ++nt)
                bf[nt] = *(const bf16x8*)(&Bh[boff + nt * 512]);
#pragma unroll
            for (int mt = 0; mt < 4; ++mt)
#pragma unroll
                for (int nt = 0; nt < 4; ++nt)
                    acc[mt][nt] = __builtin_amdgcn_mfma_f32_16x16x32_bf16(
                        af[mt], bf[nt], acc[mt][nt], 0, 0, 0);
        }
        __syncthreads();   // retires this tile's reads; drains next tile's DMA
    }
}

// Generic epilogue variant: C = f(A@W^T + bias) (+resid), fp32 or bf16 out.
template<bool OUTF32>
__global__ __launch_bounds__(512, 2) void gemm256(
    const u16* __restrict__ A, const u16* __restrict__ W,
    const float* __restrict__ bias, const float* __restrict__ resid,
    void* __restrict__ Cp, int M, int N, int K, int ldw, int do_relu)
{
    __shared__ u16 smem[49152];                 // 96 KB: 2 x (A 16KB + B 32KB)
    int tid  = threadIdx.x;
    int lane = tid & 63, wave = tid >> 6;
    int quad = lane >> 4, l16 = lane & 15;
    int wm = wave >> 2, wn = wave & 3;
    const int row_a0 = blockIdx.x * 128, row_w0 = blockIdx.y * 256;
    f32x4 acc[4][4] = {};
    gemm256_core(A, W, K, ldw, row_a0, row_w0, smem, acc);
#pragma unroll
    for (int mt = 0; mt < 4; ++mt) {
#pragma unroll
        for (int nt = 0; nt < 4; ++nt) {
#pragma unroll
            for (int r = 0; r < 4; ++r) {
                int grow = row_a0 + wm * 64 + mt * 16 + quad * 4 + r;
                int gcol = row_w0 + wn * 64 + nt * 16 + l16;
                float vv = acc[mt][nt][r];
                if (bias)    vv += bias[gcol];
                if (do_relu) vv = vv > 0.f ? vv : 0.f;
                if (resid)   vv += resid[(size_t)grow * N + gcol];
                if (OUTF32) ((float*)Cp)[(size_t)grow * N + gcol] = vv;
                else        ((u16*)Cp)[(size_t)grow * N + gcol] = f2bf(vv);
            }
        }
    }
}

// QKV-fused variant: W is stacked [3072 x 1024]; segment -> q/k/v output.
// BN=256 divides 1024, so a tile never crosses a q/k/v boundary.
__global__ __launch_bounds__(512, 2) void gemm256_qkv(
    const u16* __restrict__ A, const u16* __restrict__ Wqkv,
    u16* __restrict__ qo, u16* __restrict__ ko, u16* __restrict__ vo, int K)
{
    __shared__ u16 smem[49152];
    int tid  = threadIdx.x;
    int lane = tid & 63, wave = tid >> 6;
    int quad = lane >> 4, l16 = lane & 15;
    int wm = wave >> 2, wn = wave & 3;
    const int row_a0 = blockIdx.x * 128, row_w0 = blockIdx.y * 256;
    f32x4 acc[4][4] = {};
    gemm256_core(A, Wqkv, K, K, row_a0, row_w0, smem, acc);
    int seg = row_w0 >> 10;
    u16* dst = (seg == 0) ? qo : (seg == 1) ? ko : vo;
    int col0 = row_w0 & 1023;
#pragma unroll
    for (int mt = 0; mt < 4; ++mt) {
#pragma unroll
        for (int nt = 0; nt < 4; ++nt) {
#pragma unroll
            for (int r = 0; r < 4; ++r) {
                int grow = row_a0 + wm * 64 + mt * 16 + quad * 4 + r;
                int gcol = col0 + wn * 64 + nt * 16 + l16;
                dst[(size_t)grow * 1024 + gcol] = f2bf(acc[mt][nt][r]);
            }
        }
    }
}

// -------- MFMA flash attention v4: 32 q-rows/wave, 256-q blocks ---------------
// (unchanged from round 3 — control; LDS-BW-bound at ~95%, 131.5 us)
__global__ __launch_bounds__(512, 4) void attn_kernel(
    const u16* __restrict__ Q, const u16* __restrict__ Km, const u16* __restrict__ Vm,
    const int* __restrict__ mask, u16* __restrict__ O)
{
    const int S = 2048, DM = 1024;
    const float C1 = 0.18033688f;      // 0.125 * log2(e)
    const float C0 = -11.541560f;      // -8 * log2(e)
    __shared__ u16 smem[35840];        // 71,680 B -> 2 blocks/CU
    u16* Ks0 = smem;                   // [64*64] swizzled 16B chunks
    u16* Ks1 = smem + 4096;
    u16* Vt0 = smem + 8192;            // [64][72]
    u16* Vt1 = smem + 12800;
    u16* Ps  = smem + 17408;           // [256][72] wave-private rows
    u16* Qs  = smem + 17408;           // alias: Qs dead before Ps written

    int qt = blockIdx.x, bh = blockIdx.y;
    int b = bh >> 4, h = bh & 15;
    int tid = threadIdx.x;
    int wave = tid >> 6, lane = tid & 63;
    int quad = lane >> 4, l16 = lane & 15;
    size_t base = (size_t)b * S;
    size_t hoff = (size_t)h * 64;

    {   // stage Q tile [256 q][64 d]: 32 u16 per thread
        int r = tid >> 1, c0 = (tid & 1) * 32;
        const u16* src = Q + (base + qt * 256 + r) * DM + hoff + c0;
        u16* dq = Qs + r * 72 + c0;
        *(u16x8*)(dq)      = *(const u16x8*)(src);
        *(u16x8*)(dq + 8)  = *(const u16x8*)(src + 8);
        *(u16x8*)(dq + 16) = *(const u16x8*)(src + 16);
        *(u16x8*)(dq + 24) = *(const u16x8*)(src + 24);
    }
    const u16* ksrc = Km + (base + (tid >> 3)) * DM + hoff
                    + ((tid & 7) ^ ((tid >> 5) & 7)) * 8;
    int kp = tid & 31, d0 = (tid >> 5) * 4;
    const u16* vsrc = Vm + (base + kp * 2) * DM + hoff + d0;
    const int* msrc = mask + b * S + 4 * l16;

    __syncthreads();
    const int q0 = wave * 32;
    bf16x8 qf00 = *(const bf16x8*)(&Qs[(q0 + l16) * 72 + quad * 8]);
    bf16x8 qf01 = *(const bf16x8*)(&Qs[(q0 + l16) * 72 + 32 + quad * 8]);
    bf16x8 qf10 = *(const bf16x8*)(&Qs[(q0 + 16 + l16) * 72 + quad * 8]);
    bf16x8 qf11 = *(const bf16x8*)(&Qs[(q0 + 16 + l16) * 72 + 32 + quad * 8]);
    const int swz = (l16 & 7) * 8;
    const int u0  = (quad * 8) ^ swz;

    {   // prologue: stage tile 0 into Ks0/Vt0
        u16x4 va = *(const u16x4*)(vsrc);
        u16x4 vb = *(const u16x4*)(vsrc + DM);
        gload_lds16(ksrc, Ks0 + tid * 8);
        ksrc += 64 * DM; vsrc += 64 * DM;
#pragma unroll
        for (int i = 0; i < 4; ++i) {
            uint32_t w = (uint32_t)va[i] | ((uint32_t)vb[i] << 16);
            *(uint32_t*)(&Vt0[(d0 + i) * 72 + kp * 2]) = w;
        }
    }
    __syncthreads();

    float l0[4] = {0.f, 0.f, 0.f, 0.f};
    float l1[4] = {0.f, 0.f, 0.f, 0.f};
    f32x4 o0[4] = {}, o1[4] = {};

    for (int it = 0; it < 32; ++it) {
        const u16* Kcur = (it & 1) ? Ks1 : Ks0;
        const u16* Vcur = (it & 1) ? Vt1 : Vt0;
        u16* Knxt = (it & 1) ? Ks0 : Ks1;
        u16* Vnxt = (it & 1) ? Vt0 : Vt1;
        const bool pfch = (it < 31);
        u16x4 va, vb;
        if (pfch) {
            va = *(const u16x4*)(vsrc);
            vb = *(const u16x4*)(vsrc + DM);
            gload_lds16(ksrc, Knxt + tid * 8);
            ksrc += 64 * DM; vsrc += 64 * DM;
        }
        f32x4 s0[4] = {}, s1[4] = {};
#pragma unroll
        for (int t = 0; t < 4; ++t) {
            const u16* krp = Kcur + (4 * l16 + t) * 64;
            bf16x8 kf0 = *(const bf16x8*)(krp + u0);
            bf16x8 kf1 = *(const bf16x8*)(krp + (u0 ^ 32));
            s0[t] = __builtin_amdgcn_mfma_f32_16x16x32_bf16(qf00, kf0, s0[t], 0, 0, 0);
            s0[t] = __builtin_amdgcn_mfma_f32_16x16x32_bf16(qf01, kf1, s0[t], 0, 0, 0);
            s1[t] = __builtin_amdgcn_mfma_f32_16x16x32_bf16(qf10, kf0, s1[t], 0, 0, 0);
            s1[t] = __builtin_amdgcn_mfma_f32_16x16x32_bf16(qf11, kf1, s1[t], 0, 0, 0);
        }
        int4 mk4 = *(const int4*)(msrc); msrc += 64;
        float c0t[4];
        c0t[0] = (mk4.x == 0) ? -1e38f : C0;
        c0t[1] = (mk4.y == 0) ? -1e38f : C0;
        c0t[2] = (mk4.z == 0) ? -1e38f : C0;
        c0t[3] = (mk4.w == 0) ? -1e38f : C0;
#pragma unroll
        for (int r = 0; r < 4; ++r) {
            float p0 = exp2f(fmaf(s0[0][r], C1, c0t[0]));
            float p1 = exp2f(fmaf(s0[1][r], C1, c0t[1]));
            float p2 = exp2f(fmaf(s0[2][r], C1, c0t[2]));
            float p3 = exp2f(fmaf(s0[3][r], C1, c0t[3]));
            l0[r] += (p0 + p1) + (p2 + p3);
            uint2 pw;
            pw.x = cvt_pk_bf16(p0, p1);
            pw.y = cvt_pk_bf16(p2, p3);
            *(uint2*)(&Ps[(q0 + quad * 4 + r) * 72 + 4 * l16]) = pw;
        }
#pragma unroll
        for (int r = 0; r < 4; ++r) {
            float p0 = exp2f(fmaf(s1[0][r], C1, c0t[0]));
            float p1 = exp2f(fmaf(s1[1][r], C1, c0t[1]));
            float p2 = exp2f(fmaf(s1[2][r], C1, c0t[2]));
            float p3 = exp2f(fmaf(s1[3][r], C1, c0t[3]));
            l1[r] += (p0 + p1) + (p2 + p3);
            uint2 pw;
            pw.x = cvt_pk_bf16(p0, p1);
            pw.y = cvt_pk_bf16(p2, p3);
            *(uint2*)(&Ps[(q0 + 16 + quad * 4 + r) * 72 + 4 * l16]) = pw;
        }
        bf16x8 pf00 = *(const bf16x8*)(&Ps[(q0 + l16) * 72 + quad * 8]);
        bf16x8 pf01 = *(const bf16x8*)(&Ps[(q0 + l16) * 72 + 32 + quad * 8]);
        bf16x8 pf10 = *(const bf16x8*)(&Ps[(q0 + 16 + l16) * 72 + quad * 8]);
        bf16x8 pf11 = *(const bf16x8*)(&Ps[(q0 + 16 + l16) * 72 + 32 + quad * 8]);
#pragma unroll
        for (int t = 0; t < 4; ++t) {
            bf16x8 vf0 = *(const bf16x8*)(&Vcur[(t * 16 + l16) * 72 + quad * 8]);
            bf16x8 vf1 = *(const bf16x8*)(&Vcur[(t * 16 + l16) * 72 + 32 + quad * 8]);
            o0[t] = __builtin_amdgcn_mfma_f32_16x16x32_bf16(pf00, vf0, o0[t], 0, 0, 0);
            o0[t] = __builtin_amdgcn_mfma_f32_16x16x32_bf16(pf01, vf1, o0[t], 0, 0, 0);
            o1[t] = __builtin_amdgcn_mfma_f32_16x16x32_bf16(pf10, vf0, o1[t], 0, 0, 0);
            o1[t] = __builtin_amdgcn_mfma_f32_16x16x32_bf16(pf11, vf1, o1[t], 0, 0, 0);
        }
        if (pfch) {
#pragma unroll
            for (int i = 0; i < 4; ++i) {
                uint32_t w = (uint32_t)va[i] | ((uint32_t)vb[i] << 16);
                *(uint32_t*)(&Vnxt[(d0 + i) * 72 + kp * 2]) = w;
            }
        }
        __syncthreads();
    }
#pragma unroll
    for (int r = 0; r < 4; ++r) {
#pragma unroll
        for (int off = 1; off < 16; off <<= 1) {
            l0[r] += __shfl_xor(l0[r], off, 16);
            l1[r] += __shfl_xor(l1[r], off, 16);
        }
        float i0 = 1.0f / l0[r];
        float i1 = 1.0f / l1[r];
        u16* dst0 = O + (base + qt * 256 + q0 + quad * 4 + r) * DM + hoff + l16;
        u16* dst1 = dst0 + (size_t)16 * DM;
#pragma unroll
        for (int t = 0; t < 4; ++t) {
            dst0[t * 16] = f2bf(o0[t][r] * i0);
            dst1[t * 16] = f2bf(o1[t][r] * i1);
        }
    }
}

// -------------------------------------------------------------------------------
// Workspace budget: 72 MB (proven). ws[0..6)MB wq|wk|wv stacked; ws[6..8) wo;
// ws[8..24) w1,w2; ws[24..40) xn; ws[40..56) q; ws[40..72) hb.
// d_out doubles as k/v (bf16) then x1 (fp32).
extern "C" void kernel_launch(void* const* d_in, const int* in_sizes, int n_in,
                              void* d_out, int out_size, void* d_ws, size_t ws_size,
                              hipStream_t stream)
{
    (void)in_sizes; (void)n_in; (void)out_size; (void)ws_size;
    const float* x    = (const float*)d_in[0];
    const int*   mask = (const int*)d_in[1];
    const float* wq   = (const float*)d_in[2];
    const float* wk   = (const float*)d_in[3];
    const float* wv   = (const float*)d_in[4];
    const float* wo   = (const float*)d_in[5];
    const float* ln1a = (const float*)d_in[6];
    const float* ln1b = (const float*)d_in[7];
    const float* ln2a = (const float*)d_in[8];
    const float* ln2b = (const float*)d_in[9];
    const float* w1   = (const float*)d_in[10];
    const float* b1   = (const float*)d_in[11];
    const float* w2   = (const float*)d_in[12];
    const float* b2   = (const float*)d_in[13];

    const int M = 8192, D = 1024, F = 4096;
    char* ws = (char*)d_ws;
    u16*  wqkv = (u16*)(ws);                  // stacked 3072x1024
    u16*  wqb = wqkv;
    u16*  wkb = (u16*)(ws + (2u  << 20));
    u16*  wvb = (u16*)(ws + (4u  << 20));
    u16*  wob = (u16*)(ws + (6u  << 20));
    u16*  w1b = (u16*)(ws + (8u  << 20));
    u16*  w2b = (u16*)(ws + (16u << 20));
    u16*  xn  = (u16*)(ws + (24u << 20));     // xn1 / attn_out / xn2
    u16*  q   = (u16*)(ws + (40u << 20));
    u16*  hb  = (u16*)(ws + (40u << 20));     // overlaps q (q dead by FF1)

    u16*   kbuf = (u16*)d_out;
    u16*   vbuf = (u16*)d_out + (size_t)M * D;
    float* x1   = (float*)d_out;

    cvt_all<<<12288, 256, 0, stream>>>(wq, wk, wv, wo, w1, w2,
                                       wqb, wkb, wvb, wob, w1b, w2b);

    ln_kernel<<<M / 4, 256, 0, stream>>>(x, ln1a, ln1b, xn);
    dim3 gq(M / 128, 3072 / 256);             // 64 x 12 = 768 (3 full rounds)
    gemm256_qkv<<<gq, 512, 0, stream>>>(xn, wqkv, q, kbuf, vbuf, D);
    dim3 ga(2048 / 256, 64);
    attn_kernel<<<ga, 512, 0, stream>>>(q, kbuf, vbuf, mask, xn);
    dim3 g1(M / 128, D / 256);                // 64 x 4 = 256 (1 full round)
    gemm256<true ><<<g1, 512, 0, stream>>>(xn, wob, nullptr, x, x1, M, D, D, D, 0);
    ln_kernel<<<M / 4, 256, 0, stream>>>(x1, ln2a, ln2b, xn);
    dim3 gf1(M / 128, 2048 / 256);            // 64 x 8 = 512 (2 full rounds)
    dim3 gf2(M / 128, D / 256);               // 64 x 4 = 256
    gemm256<false><<<gf1, 512, 0, stream>>>(xn, w1b, b1, nullptr, hb, M, 2048, D, D, 1);
    gemm256<true ><<<gf2, 512, 0, stream>>>(hb, w2b, nullptr, x1, x1, M, D, 2048, F, 0);
    gemm256<false><<<gf1, 512, 0, stream>>>(xn, w1b + (size_t)2048 * D, b1 + 2048, nullptr, hb, M, 2048, D, D, 1);
    gemm256<true ><<<gf2, 512, 0, stream>>>(hb, w2b + 2048, b2, x1, x1, M, D, 2048, F, 0);
}